// Round 7
// baseline (297.560 us; speedup 1.0000x reference)
//
#include <hip/hip_runtime.h>
#include <math.h>

#define NQ      6400
#define NCAMS   6
#define LTOT    7979
#define DM      256
#define DFFN    1024

typedef __attribute__((ext_vector_type(8))) short bf16x8;
typedef __attribute__((ext_vector_type(4))) float f32x4;
typedef __attribute__((ext_vector_type(2))) float f32x2;

__device__ inline unsigned short f32_to_bf16(float f) {
    unsigned u = __float_as_uint(f);
    unsigned r = u + 0x7FFF + ((u >> 16) & 1);   // round-to-nearest-even
    return (unsigned short)(r >> 16);
}

// pack 2 f32 -> 2 bf16 in one VALU op (RNE, same rounding as f32_to_bf16)
__device__ inline unsigned cvt_pk_bf16(float lo, float hi) {
    unsigned r;
    asm("v_cvt_pk_bf16_f32 %0, %1, %2" : "=v"(r) : "v"(lo), "v"(hi));
    return r;
}
// single f32 -> bf16 in one VALU op
__device__ inline unsigned short cvt1_bf16(float x) {
    return (unsigned short)cvt_pk_bf16(x, 0.f);
}

// ---------------------------------------------------------------------------
// wt_head: transpose+convert only the weights the head kernel needs.
// wsT layout (shorts): WvT@0, WqT@65536 ([384][256]). 160 blocks.
// ---------------------------------------------------------------------------
__global__ __launch_bounds__(256) void wt_head_kernel(
    const float* __restrict__ Wv, const float* __restrict__ Woff,
    const float* __restrict__ Wattn, unsigned short* __restrict__ wsT)
{
    int b = blockIdx.x;
    const float* src; int K, N, t0, dstoff;
    if (b < 64)       { src = Wv;    K = 256; N = 256; t0 = 0;   dstoff = 0; }
    else if (b < 128) { src = Woff;  K = 256; N = 256; t0 = 64;  dstoff = 65536; }
    else              { src = Wattn; K = 256; N = 128; t0 = 128; dstoff = 131072; }
    int t = b - t0;
    int ntn = N >> 5;
    int kt = t / ntn, nt = t - kt * ntn;
    __shared__ float tile[32][33];
    int tx = threadIdx.x & 31, ty = threadIdx.x >> 5;
    #pragma unroll
    for (int i = 0; i < 4; ++i)
        tile[ty + i * 8][tx] = src[(size_t)(kt * 32 + ty + i * 8) * N + nt * 32 + tx];
    __syncthreads();
    #pragma unroll
    for (int i = 0; i < 4; ++i) {
        int nn = nt * 32 + ty + i * 8;
        wsT[dstoff + (size_t)nn * K + kt * 32 + tx] = f32_to_bf16(tile[tx][ty + i * 8]);
    }
}

// ---------------------------------------------------------------------------
// head_kernel: merged value projection + query projections.
//  b <  750 : value proj (BM=BN=128) -> vb FP8 e4m3 head-major
//             (cam, head, pixel, 32ch PERMUTED c' = 2*(c&15)+(c>>4)), 32 B rows.
//  else     : query projections (BM=64): bx=0,1 -> qoff (bf16);
//             bx=2 -> softmax -> qaw (bf16)
// A-staging fp32->bf16 uses v_cvt_pk_bf16_f32 (1 VALU / 2 elems).
// ---------------------------------------------------------------------------
__global__ __launch_bounds__(256) void head_kernel(
    const float* __restrict__ value, const float* __restrict__ query,
    const unsigned short* __restrict__ WvT, const unsigned short* __restrict__ WqT,
    const float* __restrict__ bv, const float* __restrict__ boff,
    const float* __restrict__ battn,
    unsigned char* __restrict__ vb, unsigned short* __restrict__ qoffb,
    unsigned short* __restrict__ qawb)
{
    __shared__ __align__(16) unsigned char smem[20480];
    const int b = blockIdx.x;
    const int tid = threadIdx.x;
    const int wave = tid >> 6, lane = tid & 63;
    const int wm = wave >> 1, wn = wave & 1;
    const int quad = lane >> 4, l16 = lane & 15;

    if (b < 750) {
        unsigned short (*As)[40] = (unsigned short(*)[40])smem;
        unsigned short (*Bs)[40] = (unsigned short(*)[40])(smem + 10240);
        const int m0 = (b >> 1) * 128, n0 = (b & 1) * 128;
        const int M = NCAMS * LTOT;

        f32x4 acc[4][4] = {};

        for (int k0 = 0; k0 < 256; k0 += 32) {
            #pragma unroll
            for (int i = 0; i < 2; ++i) {          // A: 128x32 fp32 -> bf16
                int idx = tid + 256 * i;
                int r = idx >> 2, kc = (idx & 3) * 8;
                int gr = m0 + r;
                float4 f0, f1;
                if (gr < M) {
                    f0 = *(const float4*)(value + (size_t)gr * 256 + k0 + kc);
                    f1 = *(const float4*)(value + (size_t)gr * 256 + k0 + kc + 4);
                } else { f0 = make_float4(0.f,0.f,0.f,0.f); f1 = f0; }
                uint4 o;
                o.x = cvt_pk_bf16(f0.x, f0.y);
                o.y = cvt_pk_bf16(f0.z, f0.w);
                o.z = cvt_pk_bf16(f1.x, f1.y);
                o.w = cvt_pk_bf16(f1.z, f1.w);
                *(uint4*)&As[r][kc] = o;
            }
            #pragma unroll
            for (int i = 0; i < 2; ++i) {          // B: WvT bf16, uint4
                int idx = tid + 256 * i;
                int r = idx >> 2, kc = (idx & 3) * 8;
                *(uint4*)&Bs[r][kc] = *(const uint4*)(WvT + (size_t)(n0 + r) * 256 + k0 + kc);
            }
            __syncthreads();
            bf16x8 af[4], bfr[4];
            #pragma unroll
            for (int mi = 0; mi < 4; ++mi)
                af[mi] = *(const bf16x8*)&As[wm * 64 + mi * 16 + l16][quad * 8];
            #pragma unroll
            for (int ni = 0; ni < 4; ++ni)
                bfr[ni] = *(const bf16x8*)&Bs[wn * 64 + ni * 16 + l16][quad * 8];
            #pragma unroll
            for (int mi = 0; mi < 4; ++mi)
                #pragma unroll
                for (int ni = 0; ni < 4; ++ni)
                    acc[mi][ni] = __builtin_amdgcn_mfma_f32_16x16x32_bf16(
                        af[mi], bfr[ni], acc[mi][ni], 0, 0, 0);
            __syncthreads();
        }

        // epilogue: pack channel pairs (c, c+16) -> adjacent bytes (2c', 2c'+1)
        #pragma unroll
        for (int mi = 0; mi < 4; ++mi) {
            #pragma unroll
            for (int r = 0; r < 4; ++r) {
                int gm = m0 + wm * 64 + mi * 16 + quad * 4 + r;
                if (gm >= M) continue;
                int cam = gm / LTOT;
                int pix = gm - cam * LTOT;
                #pragma unroll
                for (int p = 0; p < 2; ++p) {
                    int gn0 = n0 + wn * 64 + p * 32 + l16;   // c = l16 (mod 32)
                    int head = gn0 >> 5;
                    float v0 = acc[mi][2 * p][r]     + bv[gn0];
                    float v1 = acc[mi][2 * p + 1][r] + bv[gn0 + 16];
                    int pk = __builtin_amdgcn_cvt_pk_fp8_f32(v0, v1, 0, false);
                    *(unsigned short*)(vb + (((size_t)(cam * 8 + head)) * LTOT + pix) * 32
                                       + 2 * l16) = (unsigned short)pk;
                }
            }
        }
    } else {
        unsigned short (*As)[40] = (unsigned short(*)[40])smem;
        unsigned short (*Bs)[40] = (unsigned short(*)[40])(smem + 5120);
        const int t = b - 750;
        const int bx = t / 100, by = t % 100;
        const int m0 = by * 64, n0 = bx * 128;
        const int is_attn = (bx == 2);

        f32x4 acc[2][4] = {};

        for (int k0 = 0; k0 < 256; k0 += 32) {
            {                                       // A: 64x32 fp32 -> bf16
                int r = tid >> 2, kc = (tid & 3) * 8;
                float4 f0 = *(const float4*)(query + (size_t)(m0 + r) * 256 + k0 + kc);
                float4 f1 = *(const float4*)(query + (size_t)(m0 + r) * 256 + k0 + kc + 4);
                uint4 o;
                o.x = cvt_pk_bf16(f0.x, f0.y);
                o.y = cvt_pk_bf16(f0.z, f0.w);
                o.z = cvt_pk_bf16(f1.x, f1.y);
                o.w = cvt_pk_bf16(f1.z, f1.w);
                *(uint4*)&As[r][kc] = o;
            }
            #pragma unroll
            for (int i = 0; i < 2; ++i) {           // B: WqT bf16, uint4
                int idx = tid + 256 * i;
                int r = idx >> 2, kc = (idx & 3) * 8;
                *(uint4*)&Bs[r][kc] = *(const uint4*)(WqT + (size_t)(n0 + r) * 256 + k0 + kc);
            }
            __syncthreads();
            bf16x8 af[2], bfr[4];
            #pragma unroll
            for (int mi = 0; mi < 2; ++mi)
                af[mi] = *(const bf16x8*)&As[wm * 32 + mi * 16 + l16][quad * 8];
            #pragma unroll
            for (int ni = 0; ni < 4; ++ni)
                bfr[ni] = *(const bf16x8*)&Bs[wn * 64 + ni * 16 + l16][quad * 8];
            #pragma unroll
            for (int mi = 0; mi < 2; ++mi)
                #pragma unroll
                for (int ni = 0; ni < 4; ++ni)
                    acc[mi][ni] = __builtin_amdgcn_mfma_f32_16x16x32_bf16(
                        af[mi], bfr[ni], acc[mi][ni], 0, 0, 0);
            __syncthreads();
        }

        if (is_attn) {
            #pragma unroll
            for (int mi = 0; mi < 2; ++mi) {
                #pragma unroll
                for (int r = 0; r < 4; ++r) {
                    int gm = m0 + wm * 32 + mi * 16 + quad * 4 + r;
                    #pragma unroll
                    for (int ni = 0; ni < 4; ++ni) {
                        int gn = wn * 64 + ni * 16 + l16;
                        float v = acc[mi][ni][r] + battn[gn];
                        float mx = v;
                        #pragma unroll
                        for (int s = 1; s < 16; s <<= 1)
                            mx = fmaxf(mx, __shfl_xor(mx, s, 64));
                        float e = __expf(v - mx);
                        float sum = e;
                        #pragma unroll
                        for (int s = 1; s < 16; s <<= 1)
                            sum += __shfl_xor(sum, s, 64);
                        qawb[(size_t)gm * 128 + gn] = f32_to_bf16(e / sum);
                    }
                }
            }
        } else {
            #pragma unroll
            for (int mi = 0; mi < 2; ++mi) {
                #pragma unroll
                for (int r = 0; r < 4; ++r) {
                    int gm = m0 + wm * 32 + mi * 16 + quad * 4 + r;
                    #pragma unroll
                    for (int ni = 0; ni < 4; ++ni) {
                        int gn = n0 + wn * 64 + ni * 16 + l16;
                        qoffb[(size_t)gm * 256 + gn] = f32_to_bf16(acc[mi][ni][r] + boff[gn]);
                    }
                }
            }
        }
    }
}

// ---------------------------------------------------------------------------
// sample_kernel: b < 3200 -> head-partitioned fp8 deformable sampling with
// packed f32x2 accumulation; b >= 3200 -> tail weight transpose
// (Wout/W1/W2 -> WoT/W1T/W2T), overlapped with the sampling tail.
// UNCHANGED from the verified 48.8 us version.
// ---------------------------------------------------------------------------
__global__ __launch_bounds__(256) void sample_kernel(
    const unsigned char* __restrict__ vb,  // (6, 8, 7979, 32) fp8 e4m3, ch-permuted
    const unsigned short* __restrict__ qoffb, // (6400, 256) bf16
    const unsigned short* __restrict__ qawb,  // (6400, 128) bf16
    const float* __restrict__ refpts,      // (6, 1, 6400, 4, 2)
    const int*   __restrict__ bev_mask,    // (6, 1, 6400, 4)
    const float* __restrict__ Wout, const float* __restrict__ W1,
    const float* __restrict__ W2,
    unsigned short* __restrict__ outsum,   // (6400, 256) bf16 (ch-permuted)
    float* __restrict__ visb,              // (6400)
    unsigned short* __restrict__ wsT)
{
    __shared__ __align__(16) unsigned s_tab[NCAMS][272][4];   // [cam][sq*17+tup][corner]
    __shared__ float s_vis[NCAMS][16];
    __shared__ int   s_nvis[16];

    const int bid = blockIdx.x;
    const int tid = threadIdx.x;

    if (bid >= 3200) {
        // ---- tail weight transpose (reuses s_tab as the LDS tile) ----
        int t = bid - 3200;
        const float* src; int K, N, dstoff;
        if (t < 64)       { src = Wout; K = 256;  N = 256;  dstoff = 163840; }
        else if (t < 320) { src = W1;   K = 256;  N = 1024; dstoff = 229376; t -= 64; }
        else              { src = W2;   K = 1024; N = 256;  dstoff = 491520; t -= 320; }
        int ntn = N >> 5;
        int kt = t / ntn, nt = t - kt * ntn;
        float (*tile)[33] = (float(*)[33])&s_tab[0][0][0];
        int tx = tid & 31, ty = tid >> 5;
        #pragma unroll
        for (int i = 0; i < 4; ++i)
            tile[ty + i * 8][tx] = src[(size_t)(kt * 32 + ty + i * 8) * N + nt * 32 + tx];
        __syncthreads();
        // WoT only: permute K index within each 32-channel head block to match
        // the vb/outsum channel interleave: c' = 2*(c&15) | (c>>4)
        int txp = (dstoff == 163840) ? (((tx & 15) << 1) | (tx >> 4)) : tx;
        #pragma unroll
        for (int i = 0; i < 4; ++i) {
            int nn = nt * 32 + ty + i * 8;
            wsT[dstoff + (size_t)nn * K + kt * 32 + txp] = f32_to_bf16(tile[tx][ty + i * 8]);
        }
        return;
    }

    const int h   = bid & 7;
    const int q0  = (bid >> 3) * 16;
    const int sq  = tid >> 4;
    const int tup = tid & 15;
    const int lvl = tup >> 2;
    const int n_s = q0 + sq;

    if (tid < 96) {
        int cam = tid >> 4, q = tid & 15;
        const int* bm = bev_mask + ((size_t)cam * NQ + q0 + q) * 4;
        s_vis[cam][q] = ((bm[0] + bm[1] + bm[2] + bm[3]) > 0) ? 1.f : 0.f;
    }
    __syncthreads();
    if (tid >= 32 && tid < 48) {
        int q = tid - 32;
        float s = 0.f;
        #pragma unroll
        for (int cam = 0; cam < NCAMS; ++cam) s += s_vis[cam][q];
        s_nvis[q] = (int)s;
    }

    unsigned uoff = *(const unsigned*)(qoffb + (size_t)n_s * 256 + h * 32 + tup * 2);
    const float offx  = __uint_as_float(uoff << 16);
    const float offy  = __uint_as_float(uoff & 0xFFFF0000u);
    const float my_aw = __uint_as_float((unsigned)qawb[(size_t)n_s * 128 + h * 16 + tup] << 16);
    const int Wl   = (lvl == 0) ? 100 : (lvl == 1) ? 50 : (lvl == 2) ? 25 : 13;
    const int Hl   = (lvl == 0) ? 60  : (lvl == 1) ? 30 : (lvl == 2) ? 15 : 8;
    const int base = (lvl == 0) ? 0   : (lvl == 1) ? 6000 : (lvl == 2) ? 7500 : 7875;
    const float dx = offx / (float)Wl;
    const float dy = offy / (float)Hl;
    const int tabi = sq * 17 + tup;

    float2 rp[NCAMS];
    #pragma unroll
    for (int k = 0; k < NCAMS; ++k)
        rp[k] = *(const float2*)(refpts + (((size_t)k * NQ + n_s) * 4 + lvl) * 2);
    __syncthreads();   // covers s_nvis writes

    #pragma unroll
    for (int k = 0; k < NCAMS; ++k) {
        float fx = (rp[k].x + dx) * (float)Wl - 0.5f;
        float fy = (rp[k].y + dy) * (float)Hl - 0.5f;
        float x0f = floorf(fx), y0f = floorf(fy);
        float lx = fx - x0f, ly = fy - y0f;
        int x0 = (int)x0f, y0 = (int)y0f;
        int x1 = x0 + 1, y1 = y0 + 1;
        float wb = my_aw * s_vis[k][sq];
        float w00 = (1.f - lx) * (1.f - ly) * wb;
        float w01 = lx * (1.f - ly) * wb;
        float w10 = (1.f - lx) * ly * wb;
        float w11 = lx * ly * wb;
        bool vx0 = (x0 >= 0) & (x0 < Wl), vx1 = (x1 >= 0) & (x1 < Wl);
        bool vy0 = (y0 >= 0) & (y0 < Hl), vy1 = (y1 >= 0) & (y1 < Hl);
        uint4 o;
        o.x = (vx0 & vy0) ? (((unsigned)(base + y0 * Wl + x0) << 16) | f32_to_bf16(w00)) : 0u;
        o.y = (vx1 & vy0) ? (((unsigned)(base + y0 * Wl + x1) << 16) | f32_to_bf16(w01)) : 0u;
        o.z = (vx0 & vy1) ? (((unsigned)(base + y1 * Wl + x0) << 16) | f32_to_bf16(w10)) : 0u;
        o.w = (vx1 & vy1) ? (((unsigned)(base + y1 * Wl + x1) << 16) | f32_to_bf16(w11)) : 0u;
        *(uint4*)&s_tab[k][tabi][0] = o;
    }
    __syncthreads();

    // ---- accumulate: tp = 8 tap-threads (2 tuples), cg2 = 2 ch-groups of 16 ----
    const int tp  = (tid >> 1) & 7;
    const int cg2 = tid & 1;

    f32x2 A[8] = {};

    #pragma unroll
    for (int k = 0; k < NCAMS; ++k) {
        const char* vkh = (const char*)vb + (size_t)(k * 8 + h) * (LTOT * 32) + cg2 * 16;
        #pragma unroll
        for (int t = 0; t < 2; ++t) {
            uint4 t4 = *(const uint4*)&s_tab[k][sq * 17 + tp * 2 + t][0];
            #pragma unroll
            for (int corner = 0; corner < 4; ++corner) {
                unsigned tc = (corner == 0) ? t4.x : (corner == 1) ? t4.y
                            : (corner == 2) ? t4.z : t4.w;
                float w = __uint_as_float(tc << 16);
                f32x2 w2 = {w, w};
                uint4 d = *(const uint4*)(vkh + ((size_t)(tc >> 16) << 5));
                A[0] += w2 * __builtin_amdgcn_cvt_pk_f32_fp8(d.x, false);
                A[1] += w2 * __builtin_amdgcn_cvt_pk_f32_fp8(d.x, true);
                A[2] += w2 * __builtin_amdgcn_cvt_pk_f32_fp8(d.y, false);
                A[3] += w2 * __builtin_amdgcn_cvt_pk_f32_fp8(d.y, true);
                A[4] += w2 * __builtin_amdgcn_cvt_pk_f32_fp8(d.z, false);
                A[5] += w2 * __builtin_amdgcn_cvt_pk_f32_fp8(d.z, true);
                A[6] += w2 * __builtin_amdgcn_cvt_pk_f32_fp8(d.w, false);
                A[7] += w2 * __builtin_amdgcn_cvt_pk_f32_fp8(d.w, true);
            }
        }
    }

    // reduce across the 8 tap-threads (lane bits 1..3)
    #pragma unroll
    for (int i = 0; i < 8; ++i) {
        float x0 = A[i].x, x1 = A[i].y;
        x0 += __shfl_xor(x0, 2, 64); x1 += __shfl_xor(x1, 2, 64);
        x0 += __shfl_xor(x0, 4, 64); x1 += __shfl_xor(x1, 4, 64);
        x0 += __shfl_xor(x0, 8, 64); x1 += __shfl_xor(x1, 8, 64);
        A[i].x = x0; A[i].y = x1;
    }

    if ((tid & 14) == 0) {          // tp == 0: two writers per query (cg2 = 0,1)
        int nv = s_nvis[sq];
        float sc = 1.f / (float)(nv > 0 ? nv : 1);
        uint4 o0, o1;
        o0.x = f32_to_bf16(A[0].x * sc) | ((unsigned)f32_to_bf16(A[0].y * sc) << 16);
        o0.y = f32_to_bf16(A[1].x * sc) | ((unsigned)f32_to_bf16(A[1].y * sc) << 16);
        o0.z = f32_to_bf16(A[2].x * sc) | ((unsigned)f32_to_bf16(A[2].y * sc) << 16);
        o0.w = f32_to_bf16(A[3].x * sc) | ((unsigned)f32_to_bf16(A[3].y * sc) << 16);
        o1.x = f32_to_bf16(A[4].x * sc) | ((unsigned)f32_to_bf16(A[4].y * sc) << 16);
        o1.y = f32_to_bf16(A[5].x * sc) | ((unsigned)f32_to_bf16(A[5].y * sc) << 16);
        o1.z = f32_to_bf16(A[6].x * sc) | ((unsigned)f32_to_bf16(A[6].y * sc) << 16);
        o1.w = f32_to_bf16(A[7].x * sc) | ((unsigned)f32_to_bf16(A[7].y * sc) << 16);
        *(uint4*)(outsum + (size_t)n_s * 256 + h * 32 + cg2 * 16)     = o0;
        *(uint4*)(outsum + (size_t)n_s * 256 + h * 32 + cg2 * 16 + 8) = o1;
    }
    if (h == 0 && tid < 16) visb[q0 + tid] = (s_nvis[tid] > 0) ? 1.f : 0.f;
}

// ---------------------------------------------------------------------------
// tail_kernel v2: fused proj+LN1+FFN1+FFN2+LN2, restructured for the
// 1-block/CU regime the 200-block grid implies:
//  - NO LDS weight staging: B fragments are loaded per-lane from global
//    (weights 1.15 MB, read by all blocks -> L2 resident). Bit-identical
//    values to the LDS path (lane l16 -> B^T row, quad -> k-slice of 8).
//  - Phase-1 A fragments loaded per-lane from outsum global (no As LDS).
//  - Only activations (xs, hs) go through LDS; barriers drop ~46 -> ~21.
//  - __launch_bounds__(256, 1): with small LDS the occupancy heuristic
//    would clamp VGPRs and spill the 96 accumulator regs (R4 disaster);
//    min-1-wave/EU lifts the cap (grid 200 = 1 block/CU regardless).
// ---------------------------------------------------------------------------
__global__ __launch_bounds__(256, 1) void tail_kernel(
    const unsigned short* __restrict__ A,   // outsum (6400,256) bf16 ch-permuted
    const unsigned short* __restrict__ BT,  // WoT [256][256] (K-permuted)
    const unsigned short* __restrict__ W1T, // [1024][256]
    const unsigned short* __restrict__ W2T, // [256][1024]
    const float* __restrict__ query, const float* __restrict__ visb,
    const float* __restrict__ b_out,
    const float* __restrict__ g1, const float* __restrict__ bln1,
    const float* __restrict__ fb1, const float* __restrict__ fb2,
    const float* __restrict__ g2, const float* __restrict__ bln2,
    float* __restrict__ out)
{
    __shared__ __align__(16) unsigned short xs[32][264];
    __shared__ __align__(16) unsigned short hs[32][136];
    __shared__ float sred[2][4][4][2];
    __shared__ float ssred[2][4][4][2];
    __shared__ float s_mu[32], s_rs[32];

    const int tid  = threadIdx.x;
    const int wave = tid >> 6, lane = tid & 63;
    const int wm = wave >> 1, wn = wave & 1;
    const int quad = lane >> 4, l16 = lane & 15;
    const int m0 = blockIdx.x * 32;
    const int arow = wm * 16 + l16;          // A-fragment row (local)

    // ---- phase 1: proj GEMM, A and B straight from global (no LDS, no barriers) ----
    f32x4 acc[8] = {};
    #pragma unroll
    for (int k0 = 0; k0 < 256; k0 += 32) {
        bf16x8 af = *(const bf16x8*)(A + (size_t)(m0 + arow) * 256 + k0 + quad * 8);
        #pragma unroll
        for (int ni = 0; ni < 8; ++ni) {
            bf16x8 bfr = *(const bf16x8*)(BT + (size_t)(wn * 128 + ni * 16 + l16) * 256
                                          + k0 + quad * 8);
            acc[ni] = __builtin_amdgcn_mfma_f32_16x16x32_bf16(af, bfr, acc[ni], 0, 0, 0);
        }
    }

    float vals[8][4];
    #pragma unroll
    for (int r = 0; r < 4; ++r) {
        int gm = m0 + wm * 16 + quad * 4 + r;
        float vs = visb[gm];
        float s = 0.f, ss = 0.f;
        #pragma unroll
        for (int ni = 0; ni < 8; ++ni) {
            int gn = wn * 128 + ni * 16 + l16;
            float v = acc[ni][r] + vs * b_out[gn]
                    + query[(size_t)gm * 256 + gn] * (1.f + vs);
            vals[ni][r] = v;
            s += v; ss += v * v;
        }
        #pragma unroll
        for (int m = 1; m < 16; m <<= 1) {
            s  += __shfl_xor(s,  m, 64);
            ss += __shfl_xor(ss, m, 64);
        }
        if (l16 == 0) {
            sred[wm][quad][r][wn]  = s;
            ssred[wm][quad][r][wn] = ss;
        }
    }
    __syncthreads();
    if (tid < 32) {
        int lwm = tid >> 4, lq = (tid >> 2) & 3, lr = tid & 3;
        float s  = sred[lwm][lq][lr][0]  + sred[lwm][lq][lr][1];
        float ss = ssred[lwm][lq][lr][0] + ssred[lwm][lq][lr][1];
        float mu = s * (1.f / 256.f);
        float var = ss * (1.f / 256.f) - mu * mu;
        s_mu[tid] = mu;
        s_rs[tid] = rsqrtf(var + 1e-5f);
    }
    __syncthreads();

    #pragma unroll
    for (int r = 0; r < 4; ++r) {
        int rowl = wm * 16 + quad * 4 + r;
        float mu = s_mu[rowl], rs = s_rs[rowl];
        #pragma unroll
        for (int ni = 0; ni < 8; ++ni) {
            int gn = wn * 128 + ni * 16 + l16;
            float res = (vals[ni][r] - mu) * rs * g1[gn] + bln1[gn];
            vals[ni][r] = res;                       // x stays in registers
            xs[rowl][gn] = cvt1_bf16(res);           // bf16 copy for FFN1 A
        }
    }
    __syncthreads();                                  // xs visible to all

    // ---- phase 2: FFN1 -> hs -> FFN2 accumulate, per 128-col chunk ----
    f32x4 acc2[8] = {};

    for (int nc = 0; nc < 8; ++nc) {
        // FFN1: h_nc = xs @ W1T[nc*128..+128]^T  (32x128), B from global
        f32x4 hacc[4] = {};
        #pragma unroll
        for (int k0 = 0; k0 < 256; k0 += 32) {
            bf16x8 a2 = *(const bf16x8*)&xs[arow][k0 + quad * 8];
            #pragma unroll
            for (int ni = 0; ni < 4; ++ni) {
                bf16x8 b2v = *(const bf16x8*)(W1T
                    + (size_t)(nc * 128 + wn * 64 + ni * 16 + l16) * 256 + k0 + quad * 8);
                hacc[ni] = __builtin_amdgcn_mfma_f32_16x16x32_bf16(a2, b2v, hacc[ni], 0, 0, 0);
            }
        }
        __syncthreads();   // prev iteration's FFN2 reads of hs complete
        #pragma unroll
        for (int ni = 0; ni < 4; ++ni) {
            #pragma unroll
            for (int r = 0; r < 4; ++r) {
                int rowl = wm * 16 + quad * 4 + r;
                int col  = wn * 64 + ni * 16 + l16;
                hs[rowl][col] = cvt1_bf16(fmaxf(hacc[ni][r] + fb1[nc * 128 + col], 0.f));
            }
        }
        __syncthreads();   // hs visible
        // FFN2 partial: acc2 += hs @ W2T[:, nc*128..+128]^T, B from global
        #pragma unroll
        for (int ks = 0; ks < 4; ++ks) {
            bf16x8 a3 = *(const bf16x8*)&hs[arow][ks * 32 + quad * 8];
            #pragma unroll
            for (int ni = 0; ni < 8; ++ni) {
                bf16x8 b3 = *(const bf16x8*)(W2T
                    + (size_t)(wn * 128 + ni * 16 + l16) * 1024 + nc * 128 + ks * 32 + quad * 8);
                acc2[ni] = __builtin_amdgcn_mfma_f32_16x16x32_bf16(a3, b3, acc2[ni], 0, 0, 0);
            }
        }
    }

    // ---- epilogue: LN2(x + f + b2) ----
    #pragma unroll
    for (int r = 0; r < 4; ++r) {
        float s = 0.f, ss = 0.f;
        #pragma unroll
        for (int ni = 0; ni < 8; ++ni) {
            int gn = wn * 128 + ni * 16 + l16;
            float t = vals[ni][r] + acc2[ni][r] + fb2[gn];
            vals[ni][r] = t;
            s += t; ss += t * t;
        }
        #pragma unroll
        for (int m = 1; m < 16; m <<= 1) {
            s  += __shfl_xor(s,  m, 64);
            ss += __shfl_xor(ss, m, 64);
        }
        if (l16 == 0) {
            sred[wm][quad][r][wn]  = s;
            ssred[wm][quad][r][wn] = ss;
        }
    }
    __syncthreads();
    if (tid < 32) {
        int lwm = tid >> 4, lq = (tid >> 2) & 3, lr = tid & 3;
        float s  = sred[lwm][lq][lr][0]  + sred[lwm][lq][lr][1];
        float ss = ssred[lwm][lq][lr][0] + ssred[lwm][lq][lr][1];
        float mu = s * (1.f / 256.f);
        float var = ss * (1.f / 256.f) - mu * mu;
        s_mu[tid] = mu;
        s_rs[tid] = rsqrtf(var + 1e-5f);
    }
    __syncthreads();

    #pragma unroll
    for (int r = 0; r < 4; ++r) {
        int rowl = wm * 16 + quad * 4 + r;
        int gm = m0 + rowl;
        float mu = s_mu[rowl], rs = s_rs[rowl];
        #pragma unroll
        for (int ni = 0; ni < 8; ++ni) {
            int gn = wn * 128 + ni * 16 + l16;
            out[(size_t)gm * 256 + gn] = (vals[ni][r] - mu) * rs * g2[gn] + bln2[gn];
        }
    }
}

// ---------------------------------------------------------------------------
extern "C" void kernel_launch(void* const* d_in, const int* in_sizes, int n_in,
                              void* d_out, int out_size, void* d_ws, size_t ws_size,
                              hipStream_t stream)
{
    const float* query   = (const float*)d_in[0];
    const float* value   = (const float*)d_in[2];
    const float* refpts  = (const float*)d_in[3];
    const int*   bevmask = (const int*)d_in[6];
    const float* W_value = (const float*)d_in[7];
    const float* b_value = (const float*)d_in[8];
    const float* W_off   = (const float*)d_in[9];
    const float* b_off   = (const float*)d_in[10];
    const float* W_attn  = (const float*)d_in[11];
    const float* b_attn  = (const float*)d_in[12];
    const float* W_out   = (const float*)d_in[13];
    const float* b_out   = (const float*)d_in[14];
    const float* ln1_g   = (const float*)d_in[15];
    const float* ln1_b   = (const float*)d_in[16];
    const float* W1      = (const float*)d_in[17];
    const float* b1      = (const float*)d_in[18];
    const float* W2      = (const float*)d_in[19];
    const float* b2      = (const float*)d_in[20];
    const float* ln2_g   = (const float*)d_in[21];
    const float* ln2_b   = (const float*)d_in[22];
    float* out = (float*)d_out;

    // workspace layout (byte offsets):
    //  [0)          vb fp8 12,255,744       (head -> sample)
    //  [27,000,000) qoffb bf16 3,276,800    (head -> sample)
    //  [31,000,000) qawb bf16 1,638,400     (head -> sample)
    //  [33,000,000) outsum bf16 3,276,800   (sample -> tail)
    //  [36,500,000) visb 25,600             (sample -> tail)
    //  [36,600,000) wsT bf16 1,507,328      (wt_head/sample-tail -> GEMMs)
    char* ws = (char*)d_ws;
    unsigned char*  vb     = (unsigned char*)(ws + 0);
    unsigned short* qoffb  = (unsigned short*)(ws + 27000000);
    unsigned short* qawb   = (unsigned short*)(ws + 31000000);
    unsigned short* outsum = (unsigned short*)(ws + 33000000);
    float*          visb   = (float*)(ws + 36500000);
    unsigned short* wsT    = (unsigned short*)(ws + 36600000);

    unsigned short* WvT = wsT;            // [256][256]
    unsigned short* WqT = wsT + 65536;    // [384][256]
    unsigned short* WoT = wsT + 163840;   // [256][256] (K-permuted)
    unsigned short* W1T = wsT + 229376;   // [1024][256]
    unsigned short* W2T = wsT + 491520;   // [256][1024]

    // L0: head-side weights -> transposed bf16 (160 blocks)
    wt_head_kernel<<<dim3(160), 256, 0, stream>>>(
        W_value, W_off, W_attn, wsT);
    // L1: value proj (750 blocks, fp8 out, ch-permuted) + query proj (300 blocks)
    head_kernel<<<dim3(1050), 256, 0, stream>>>(
        value, query, WvT, WqT, b_value, b_off, b_attn, vb, qoffb, qawb);
    // L2: sampling (3200) + tail weight transpose (576, overlapped)
    sample_kernel<<<dim3(3776), 256, 0, stream>>>(
        vb, qoffb, qawb, refpts, bevmask, W_out, W1, W2, outsum, visb, wsT);
    // L3: fused proj+LN1+FFN1+FFN2+LN2 -> out (200 blocks)
    tail_kernel<<<dim3(200), 256, 0, stream>>>(
        outsum, WoT, W1T, W2T, query, visb, b_out,
        ln1_g, ln1_b, b1, b2, ln2_g, ln2_b, out);
}

// Round 8
// 281.211 us; speedup vs baseline: 1.0581x; 1.0581x over previous
//
#include <hip/hip_runtime.h>
#include <math.h>

#define NQ      6400
#define NCAMS   6
#define LTOT    7979
#define DM      256
#define DFFN    1024

typedef __attribute__((ext_vector_type(8))) short bf16x8;
typedef __attribute__((ext_vector_type(4))) float f32x4;
typedef __attribute__((ext_vector_type(2))) float f32x2;

__device__ inline unsigned short f32_to_bf16(float f) {
    unsigned u = __float_as_uint(f);
    unsigned r = u + 0x7FFF + ((u >> 16) & 1);   // round-to-nearest-even
    return (unsigned short)(r >> 16);
}

// pack 2 f32 -> 2 bf16 in one VALU op (RNE, same rounding as f32_to_bf16)
__device__ inline unsigned cvt_pk_bf16(float lo, float hi) {
    unsigned r;
    asm("v_cvt_pk_bf16_f32 %0, %1, %2" : "=v"(r) : "v"(lo), "v"(hi));
    return r;
}
// single f32 -> bf16 in one VALU op
__device__ inline unsigned short cvt1_bf16(float x) {
    return (unsigned short)cvt_pk_bf16(x, 0.f);
}

// ---------------------------------------------------------------------------
// wt_head: transpose+convert only the weights the head kernel needs.
// wsT layout (shorts): WvT@0, WqT@65536 ([384][256]). 160 blocks.
// ---------------------------------------------------------------------------
__global__ __launch_bounds__(256) void wt_head_kernel(
    const float* __restrict__ Wv, const float* __restrict__ Woff,
    const float* __restrict__ Wattn, unsigned short* __restrict__ wsT)
{
    int b = blockIdx.x;
    const float* src; int K, N, t0, dstoff;
    if (b < 64)       { src = Wv;    K = 256; N = 256; t0 = 0;   dstoff = 0; }
    else if (b < 128) { src = Woff;  K = 256; N = 256; t0 = 64;  dstoff = 65536; }
    else              { src = Wattn; K = 256; N = 128; t0 = 128; dstoff = 131072; }
    int t = b - t0;
    int ntn = N >> 5;
    int kt = t / ntn, nt = t - kt * ntn;
    __shared__ float tile[32][33];
    int tx = threadIdx.x & 31, ty = threadIdx.x >> 5;
    #pragma unroll
    for (int i = 0; i < 4; ++i)
        tile[ty + i * 8][tx] = src[(size_t)(kt * 32 + ty + i * 8) * N + nt * 32 + tx];
    __syncthreads();
    #pragma unroll
    for (int i = 0; i < 4; ++i) {
        int nn = nt * 32 + ty + i * 8;
        wsT[dstoff + (size_t)nn * K + kt * 32 + tx] = f32_to_bf16(tile[tx][ty + i * 8]);
    }
}

// ---------------------------------------------------------------------------
// head_kernel: merged value projection + query projections.
//  b <  750 : value proj (BM=BN=128) -> vb FP8 e4m3 head-major
//             (cam, head, pixel, 32ch PERMUTED c' = 2*(c&15)+(c>>4)), 32 B rows.
//  else     : query projections (BM=64): bx=0,1 -> qoff (bf16);
//             bx=2 -> softmax -> qaw (bf16)
// A-staging fp32->bf16 uses v_cvt_pk_bf16_f32 (1 VALU / 2 elems).
// ---------------------------------------------------------------------------
__global__ __launch_bounds__(256) void head_kernel(
    const float* __restrict__ value, const float* __restrict__ query,
    const unsigned short* __restrict__ WvT, const unsigned short* __restrict__ WqT,
    const float* __restrict__ bv, const float* __restrict__ boff,
    const float* __restrict__ battn,
    unsigned char* __restrict__ vb, unsigned short* __restrict__ qoffb,
    unsigned short* __restrict__ qawb)
{
    __shared__ __align__(16) unsigned char smem[20480];
    const int b = blockIdx.x;
    const int tid = threadIdx.x;
    const int wave = tid >> 6, lane = tid & 63;
    const int wm = wave >> 1, wn = wave & 1;
    const int quad = lane >> 4, l16 = lane & 15;

    if (b < 750) {
        unsigned short (*As)[40] = (unsigned short(*)[40])smem;
        unsigned short (*Bs)[40] = (unsigned short(*)[40])(smem + 10240);
        const int m0 = (b >> 1) * 128, n0 = (b & 1) * 128;
        const int M = NCAMS * LTOT;

        f32x4 acc[4][4] = {};

        for (int k0 = 0; k0 < 256; k0 += 32) {
            #pragma unroll
            for (int i = 0; i < 2; ++i) {          // A: 128x32 fp32 -> bf16
                int idx = tid + 256 * i;
                int r = idx >> 2, kc = (idx & 3) * 8;
                int gr = m0 + r;
                float4 f0, f1;
                if (gr < M) {
                    f0 = *(const float4*)(value + (size_t)gr * 256 + k0 + kc);
                    f1 = *(const float4*)(value + (size_t)gr * 256 + k0 + kc + 4);
                } else { f0 = make_float4(0.f,0.f,0.f,0.f); f1 = f0; }
                uint4 o;
                o.x = cvt_pk_bf16(f0.x, f0.y);
                o.y = cvt_pk_bf16(f0.z, f0.w);
                o.z = cvt_pk_bf16(f1.x, f1.y);
                o.w = cvt_pk_bf16(f1.z, f1.w);
                *(uint4*)&As[r][kc] = o;
            }
            #pragma unroll
            for (int i = 0; i < 2; ++i) {          // B: WvT bf16, uint4
                int idx = tid + 256 * i;
                int r = idx >> 2, kc = (idx & 3) * 8;
                *(uint4*)&Bs[r][kc] = *(const uint4*)(WvT + (size_t)(n0 + r) * 256 + k0 + kc);
            }
            __syncthreads();
            bf16x8 af[4], bfr[4];
            #pragma unroll
            for (int mi = 0; mi < 4; ++mi)
                af[mi] = *(const bf16x8*)&As[wm * 64 + mi * 16 + l16][quad * 8];
            #pragma unroll
            for (int ni = 0; ni < 4; ++ni)
                bfr[ni] = *(const bf16x8*)&Bs[wn * 64 + ni * 16 + l16][quad * 8];
            #pragma unroll
            for (int mi = 0; mi < 4; ++mi)
                #pragma unroll
                for (int ni = 0; ni < 4; ++ni)
                    acc[mi][ni] = __builtin_amdgcn_mfma_f32_16x16x32_bf16(
                        af[mi], bfr[ni], acc[mi][ni], 0, 0, 0);
            __syncthreads();
        }

        // epilogue: pack channel pairs (c, c+16) -> adjacent bytes (2c', 2c'+1)
        #pragma unroll
        for (int mi = 0; mi < 4; ++mi) {
            #pragma unroll
            for (int r = 0; r < 4; ++r) {
                int gm = m0 + wm * 64 + mi * 16 + quad * 4 + r;
                if (gm >= M) continue;
                int cam = gm / LTOT;
                int pix = gm - cam * LTOT;
                #pragma unroll
                for (int p = 0; p < 2; ++p) {
                    int gn0 = n0 + wn * 64 + p * 32 + l16;   // c = l16 (mod 32)
                    int head = gn0 >> 5;
                    float v0 = acc[mi][2 * p][r]     + bv[gn0];
                    float v1 = acc[mi][2 * p + 1][r] + bv[gn0 + 16];
                    int pk = __builtin_amdgcn_cvt_pk_fp8_f32(v0, v1, 0, false);
                    *(unsigned short*)(vb + (((size_t)(cam * 8 + head)) * LTOT + pix) * 32
                                       + 2 * l16) = (unsigned short)pk;
                }
            }
        }
    } else {
        unsigned short (*As)[40] = (unsigned short(*)[40])smem;
        unsigned short (*Bs)[40] = (unsigned short(*)[40])(smem + 5120);
        const int t = b - 750;
        const int bx = t / 100, by = t % 100;
        const int m0 = by * 64, n0 = bx * 128;
        const int is_attn = (bx == 2);

        f32x4 acc[2][4] = {};

        for (int k0 = 0; k0 < 256; k0 += 32) {
            {                                       // A: 64x32 fp32 -> bf16
                int r = tid >> 2, kc = (tid & 3) * 8;
                float4 f0 = *(const float4*)(query + (size_t)(m0 + r) * 256 + k0 + kc);
                float4 f1 = *(const float4*)(query + (size_t)(m0 + r) * 256 + k0 + kc + 4);
                uint4 o;
                o.x = cvt_pk_bf16(f0.x, f0.y);
                o.y = cvt_pk_bf16(f0.z, f0.w);
                o.z = cvt_pk_bf16(f1.x, f1.y);
                o.w = cvt_pk_bf16(f1.z, f1.w);
                *(uint4*)&As[r][kc] = o;
            }
            #pragma unroll
            for (int i = 0; i < 2; ++i) {           // B: WqT bf16, uint4
                int idx = tid + 256 * i;
                int r = idx >> 2, kc = (idx & 3) * 8;
                *(uint4*)&Bs[r][kc] = *(const uint4*)(WqT + (size_t)(n0 + r) * 256 + k0 + kc);
            }
            __syncthreads();
            bf16x8 af[2], bfr[4];
            #pragma unroll
            for (int mi = 0; mi < 2; ++mi)
                af[mi] = *(const bf16x8*)&As[wm * 32 + mi * 16 + l16][quad * 8];
            #pragma unroll
            for (int ni = 0; ni < 4; ++ni)
                bfr[ni] = *(const bf16x8*)&Bs[wn * 64 + ni * 16 + l16][quad * 8];
            #pragma unroll
            for (int mi = 0; mi < 2; ++mi)
                #pragma unroll
                for (int ni = 0; ni < 4; ++ni)
                    acc[mi][ni] = __builtin_amdgcn_mfma_f32_16x16x32_bf16(
                        af[mi], bfr[ni], acc[mi][ni], 0, 0, 0);
            __syncthreads();
        }

        if (is_attn) {
            #pragma unroll
            for (int mi = 0; mi < 2; ++mi) {
                #pragma unroll
                for (int r = 0; r < 4; ++r) {
                    int gm = m0 + wm * 32 + mi * 16 + quad * 4 + r;
                    #pragma unroll
                    for (int ni = 0; ni < 4; ++ni) {
                        int gn = wn * 64 + ni * 16 + l16;
                        float v = acc[mi][ni][r] + battn[gn];
                        float mx = v;
                        #pragma unroll
                        for (int s = 1; s < 16; s <<= 1)
                            mx = fmaxf(mx, __shfl_xor(mx, s, 64));
                        float e = __expf(v - mx);
                        float sum = e;
                        #pragma unroll
                        for (int s = 1; s < 16; s <<= 1)
                            sum += __shfl_xor(sum, s, 64);
                        qawb[(size_t)gm * 128 + gn] = f32_to_bf16(e / sum);
                    }
                }
            }
        } else {
            #pragma unroll
            for (int mi = 0; mi < 2; ++mi) {
                #pragma unroll
                for (int r = 0; r < 4; ++r) {
                    int gm = m0 + wm * 32 + mi * 16 + quad * 4 + r;
                    #pragma unroll
                    for (int ni = 0; ni < 4; ++ni) {
                        int gn = n0 + wn * 64 + ni * 16 + l16;
                        qoffb[(size_t)gm * 256 + gn] = f32_to_bf16(acc[mi][ni][r] + boff[gn]);
                    }
                }
            }
        }
    }
}

// ---------------------------------------------------------------------------
// sample_kernel: b < 3200 -> head-partitioned fp8 deformable sampling with
// packed f32x2 accumulation; b >= 3200 -> tail weight transpose
// (Wout/W1/W2 -> WoT/W1T/W2T), overlapped with the sampling tail.
// UNCHANGED from the verified 48.8 us version.
// ---------------------------------------------------------------------------
__global__ __launch_bounds__(256) void sample_kernel(
    const unsigned char* __restrict__ vb,  // (6, 8, 7979, 32) fp8 e4m3, ch-permuted
    const unsigned short* __restrict__ qoffb, // (6400, 256) bf16
    const unsigned short* __restrict__ qawb,  // (6400, 128) bf16
    const float* __restrict__ refpts,      // (6, 1, 6400, 4, 2)
    const int*   __restrict__ bev_mask,    // (6, 1, 6400, 4)
    const float* __restrict__ Wout, const float* __restrict__ W1,
    const float* __restrict__ W2,
    unsigned short* __restrict__ outsum,   // (6400, 256) bf16 (ch-permuted)
    float* __restrict__ visb,              // (6400)
    unsigned short* __restrict__ wsT)
{
    __shared__ __align__(16) unsigned s_tab[NCAMS][272][4];   // [cam][sq*17+tup][corner]
    __shared__ float s_vis[NCAMS][16];
    __shared__ int   s_nvis[16];

    const int bid = blockIdx.x;
    const int tid = threadIdx.x;

    if (bid >= 3200) {
        // ---- tail weight transpose (reuses s_tab as the LDS tile) ----
        int t = bid - 3200;
        const float* src; int K, N, dstoff;
        if (t < 64)       { src = Wout; K = 256;  N = 256;  dstoff = 163840; }
        else if (t < 320) { src = W1;   K = 256;  N = 1024; dstoff = 229376; t -= 64; }
        else              { src = W2;   K = 1024; N = 256;  dstoff = 491520; t -= 320; }
        int ntn = N >> 5;
        int kt = t / ntn, nt = t - kt * ntn;
        float (*tile)[33] = (float(*)[33])&s_tab[0][0][0];
        int tx = tid & 31, ty = tid >> 5;
        #pragma unroll
        for (int i = 0; i < 4; ++i)
            tile[ty + i * 8][tx] = src[(size_t)(kt * 32 + ty + i * 8) * N + nt * 32 + tx];
        __syncthreads();
        // WoT only: permute K index within each 32-channel head block to match
        // the vb/outsum channel interleave: c' = 2*(c&15) | (c>>4)
        int txp = (dstoff == 163840) ? (((tx & 15) << 1) | (tx >> 4)) : tx;
        #pragma unroll
        for (int i = 0; i < 4; ++i) {
            int nn = nt * 32 + ty + i * 8;
            wsT[dstoff + (size_t)nn * K + kt * 32 + txp] = f32_to_bf16(tile[tx][ty + i * 8]);
        }
        return;
    }

    const int h   = bid & 7;
    const int q0  = (bid >> 3) * 16;
    const int sq  = tid >> 4;
    const int tup = tid & 15;
    const int lvl = tup >> 2;
    const int n_s = q0 + sq;

    if (tid < 96) {
        int cam = tid >> 4, q = tid & 15;
        const int* bm = bev_mask + ((size_t)cam * NQ + q0 + q) * 4;
        s_vis[cam][q] = ((bm[0] + bm[1] + bm[2] + bm[3]) > 0) ? 1.f : 0.f;
    }
    __syncthreads();
    if (tid >= 32 && tid < 48) {
        int q = tid - 32;
        float s = 0.f;
        #pragma unroll
        for (int cam = 0; cam < NCAMS; ++cam) s += s_vis[cam][q];
        s_nvis[q] = (int)s;
    }

    unsigned uoff = *(const unsigned*)(qoffb + (size_t)n_s * 256 + h * 32 + tup * 2);
    const float offx  = __uint_as_float(uoff << 16);
    const float offy  = __uint_as_float(uoff & 0xFFFF0000u);
    const float my_aw = __uint_as_float((unsigned)qawb[(size_t)n_s * 128 + h * 16 + tup] << 16);
    const int Wl   = (lvl == 0) ? 100 : (lvl == 1) ? 50 : (lvl == 2) ? 25 : 13;
    const int Hl   = (lvl == 0) ? 60  : (lvl == 1) ? 30 : (lvl == 2) ? 15 : 8;
    const int base = (lvl == 0) ? 0   : (lvl == 1) ? 6000 : (lvl == 2) ? 7500 : 7875;
    const float dx = offx / (float)Wl;
    const float dy = offy / (float)Hl;
    const int tabi = sq * 17 + tup;

    float2 rp[NCAMS];
    #pragma unroll
    for (int k = 0; k < NCAMS; ++k)
        rp[k] = *(const float2*)(refpts + (((size_t)k * NQ + n_s) * 4 + lvl) * 2);
    __syncthreads();   // covers s_nvis writes

    #pragma unroll
    for (int k = 0; k < NCAMS; ++k) {
        float fx = (rp[k].x + dx) * (float)Wl - 0.5f;
        float fy = (rp[k].y + dy) * (float)Hl - 0.5f;
        float x0f = floorf(fx), y0f = floorf(fy);
        float lx = fx - x0f, ly = fy - y0f;
        int x0 = (int)x0f, y0 = (int)y0f;
        int x1 = x0 + 1, y1 = y0 + 1;
        float wb = my_aw * s_vis[k][sq];
        float w00 = (1.f - lx) * (1.f - ly) * wb;
        float w01 = lx * (1.f - ly) * wb;
        float w10 = (1.f - lx) * ly * wb;
        float w11 = lx * ly * wb;
        bool vx0 = (x0 >= 0) & (x0 < Wl), vx1 = (x1 >= 0) & (x1 < Wl);
        bool vy0 = (y0 >= 0) & (y0 < Hl), vy1 = (y1 >= 0) & (y1 < Hl);
        uint4 o;
        o.x = (vx0 & vy0) ? (((unsigned)(base + y0 * Wl + x0) << 16) | f32_to_bf16(w00)) : 0u;
        o.y = (vx1 & vy0) ? (((unsigned)(base + y0 * Wl + x1) << 16) | f32_to_bf16(w01)) : 0u;
        o.z = (vx0 & vy1) ? (((unsigned)(base + y1 * Wl + x0) << 16) | f32_to_bf16(w10)) : 0u;
        o.w = (vx1 & vy1) ? (((unsigned)(base + y1 * Wl + x1) << 16) | f32_to_bf16(w11)) : 0u;
        *(uint4*)&s_tab[k][tabi][0] = o;
    }
    __syncthreads();

    // ---- accumulate: tp = 8 tap-threads (2 tuples), cg2 = 2 ch-groups of 16 ----
    const int tp  = (tid >> 1) & 7;
    const int cg2 = tid & 1;

    f32x2 A[8] = {};

    #pragma unroll
    for (int k = 0; k < NCAMS; ++k) {
        const char* vkh = (const char*)vb + (size_t)(k * 8 + h) * (LTOT * 32) + cg2 * 16;
        #pragma unroll
        for (int t = 0; t < 2; ++t) {
            uint4 t4 = *(const uint4*)&s_tab[k][sq * 17 + tp * 2 + t][0];
            #pragma unroll
            for (int corner = 0; corner < 4; ++corner) {
                unsigned tc = (corner == 0) ? t4.x : (corner == 1) ? t4.y
                            : (corner == 2) ? t4.z : t4.w;
                float w = __uint_as_float(tc << 16);
                f32x2 w2 = {w, w};
                uint4 d = *(const uint4*)(vkh + ((size_t)(tc >> 16) << 5));
                A[0] += w2 * __builtin_amdgcn_cvt_pk_f32_fp8(d.x, false);
                A[1] += w2 * __builtin_amdgcn_cvt_pk_f32_fp8(d.x, true);
                A[2] += w2 * __builtin_amdgcn_cvt_pk_f32_fp8(d.y, false);
                A[3] += w2 * __builtin_amdgcn_cvt_pk_f32_fp8(d.y, true);
                A[4] += w2 * __builtin_amdgcn_cvt_pk_f32_fp8(d.z, false);
                A[5] += w2 * __builtin_amdgcn_cvt_pk_f32_fp8(d.z, true);
                A[6] += w2 * __builtin_amdgcn_cvt_pk_f32_fp8(d.w, false);
                A[7] += w2 * __builtin_amdgcn_cvt_pk_f32_fp8(d.w, true);
            }
        }
    }

    // reduce across the 8 tap-threads (lane bits 1..3)
    #pragma unroll
    for (int i = 0; i < 8; ++i) {
        float x0 = A[i].x, x1 = A[i].y;
        x0 += __shfl_xor(x0, 2, 64); x1 += __shfl_xor(x1, 2, 64);
        x0 += __shfl_xor(x0, 4, 64); x1 += __shfl_xor(x1, 4, 64);
        x0 += __shfl_xor(x0, 8, 64); x1 += __shfl_xor(x1, 8, 64);
        A[i].x = x0; A[i].y = x1;
    }

    if ((tid & 14) == 0) {          // tp == 0: two writers per query (cg2 = 0,1)
        int nv = s_nvis[sq];
        float sc = 1.f / (float)(nv > 0 ? nv : 1);
        uint4 o0, o1;
        o0.x = f32_to_bf16(A[0].x * sc) | ((unsigned)f32_to_bf16(A[0].y * sc) << 16);
        o0.y = f32_to_bf16(A[1].x * sc) | ((unsigned)f32_to_bf16(A[1].y * sc) << 16);
        o0.z = f32_to_bf16(A[2].x * sc) | ((unsigned)f32_to_bf16(A[2].y * sc) << 16);
        o0.w = f32_to_bf16(A[3].x * sc) | ((unsigned)f32_to_bf16(A[3].y * sc) << 16);
        o1.x = f32_to_bf16(A[4].x * sc) | ((unsigned)f32_to_bf16(A[4].y * sc) << 16);
        o1.y = f32_to_bf16(A[5].x * sc) | ((unsigned)f32_to_bf16(A[5].y * sc) << 16);
        o1.z = f32_to_bf16(A[6].x * sc) | ((unsigned)f32_to_bf16(A[6].y * sc) << 16);
        o1.w = f32_to_bf16(A[7].x * sc) | ((unsigned)f32_to_bf16(A[7].y * sc) << 16);
        *(uint4*)(outsum + (size_t)n_s * 256 + h * 32 + cg2 * 16)     = o0;
        *(uint4*)(outsum + (size_t)n_s * 256 + h * 32 + cg2 * 16 + 8) = o1;
    }
    if (h == 0 && tid < 16) visb[q0 + tid] = (s_nvis[tid] > 0) ? 1.f : 0.f;
}

// ---------------------------------------------------------------------------
// projln1 v2: BM=16, 400 blocks (was BM=32 / 200 blocks -- <1 block/CU was
// latency-exposed; 400 blocks doubles machine-wide TLP). Each wave owns a
// 64-col slice; LN1 reduction crosses 4 waves via LDS.
// x = LN(outsum@WoT + residual algebra) -> xout fp32 + xb16 bf16.
// ---------------------------------------------------------------------------
__global__ __launch_bounds__(256) void projln1_kernel(
    const unsigned short* __restrict__ A, const unsigned short* __restrict__ BT,
    const float* __restrict__ query, const float* __restrict__ visb,
    const float* __restrict__ b_out, const float* __restrict__ g,
    const float* __restrict__ b,
    float* __restrict__ xout, unsigned short* __restrict__ xb16)
{
    __shared__ __align__(16) unsigned short As[16][40];
    __shared__ __align__(16) unsigned short Bs[256][40];
    __shared__ float sred[4][4][4];    // [quad][r][wave]
    __shared__ float ssred[4][4][4];
    __shared__ float s_mu[16], s_rs[16];

    const int tid  = threadIdx.x;
    const int wave = tid >> 6, lane = tid & 63;
    const int quad = lane >> 4, l16 = lane & 15;
    const int m0 = blockIdx.x * 16;

    f32x4 acc[4] = {};

    for (int k0 = 0; k0 < 256; k0 += 32) {
        {
            int r = tid >> 4, kc = (tid & 15) * 2;
            *(unsigned*)&As[r][kc] = *(const unsigned*)(A + (size_t)(m0 + r) * 256 + k0 + kc);
        }
        {
            const unsigned short* src = BT + (size_t)tid * 256 + k0;
            *(uint4*)&Bs[tid][0]  = *(const uint4*)(src);
            *(uint4*)&Bs[tid][8]  = *(const uint4*)(src + 8);
            *(uint4*)&Bs[tid][16] = *(const uint4*)(src + 16);
            *(uint4*)&Bs[tid][24] = *(const uint4*)(src + 24);
        }
        __syncthreads();
        bf16x8 af = *(const bf16x8*)&As[l16][quad * 8];
        #pragma unroll
        for (int ni = 0; ni < 4; ++ni) {
            bf16x8 bfr = *(const bf16x8*)&Bs[wave * 64 + ni * 16 + l16][quad * 8];
            acc[ni] = __builtin_amdgcn_mfma_f32_16x16x32_bf16(af, bfr, acc[ni], 0, 0, 0);
        }
        __syncthreads();
    }

    float vals[4][4];
    #pragma unroll
    for (int r = 0; r < 4; ++r) {
        int gm = m0 + quad * 4 + r;
        float vs = visb[gm];
        float s = 0.f, ss = 0.f;
        #pragma unroll
        for (int ni = 0; ni < 4; ++ni) {
            int gn = wave * 64 + ni * 16 + l16;
            float v = acc[ni][r] + vs * b_out[gn]
                    + query[(size_t)gm * 256 + gn] * (1.f + vs);
            vals[ni][r] = v;
            s += v; ss += v * v;
        }
        #pragma unroll
        for (int m = 1; m < 16; m <<= 1) {
            s  += __shfl_xor(s,  m, 64);
            ss += __shfl_xor(ss, m, 64);
        }
        if (l16 == 0) {
            sred[quad][r][wave]  = s;
            ssred[quad][r][wave] = ss;
        }
    }
    __syncthreads();
    if (tid < 16) {
        int lq = tid >> 2, lr = tid & 3;
        float s  = sred[lq][lr][0]  + sred[lq][lr][1]  + sred[lq][lr][2]  + sred[lq][lr][3];
        float ss = ssred[lq][lr][0] + ssred[lq][lr][1] + ssred[lq][lr][2] + ssred[lq][lr][3];
        float mu = s * (1.f / 256.f);
        float var = ss * (1.f / 256.f) - mu * mu;
        s_mu[tid] = mu;                 // tid == lq*4+lr == local row
        s_rs[tid] = rsqrtf(var + 1e-5f);
    }
    __syncthreads();

    #pragma unroll
    for (int r = 0; r < 4; ++r) {
        int rowl = quad * 4 + r;
        int gm = m0 + rowl;
        float mu = s_mu[rowl], rs = s_rs[rowl];
        #pragma unroll
        for (int ni = 0; ni < 4; ++ni) {
            int gn = wave * 64 + ni * 16 + l16;
            float res = (vals[ni][r] - mu) * rs * g[gn] + b[gn];
            xout[(size_t)gm * 256 + gn] = res;
            xb16[(size_t)gm * 256 + gn] = cvt1_bf16(res);
        }
    }
}

// ---------------------------------------------------------------------------
// MFMA bf16 GEMM, BM=64 BN=128 BK=32, bf16 A + BT. Split-K over gridDim.z.
// mode 1: relu -> bf16 out; mode 2: plain bf16 out (split-K partials).
// ---------------------------------------------------------------------------
__global__ __launch_bounds__(256) void gemm64_kernel(
    const unsigned short* __restrict__ A, const unsigned short* __restrict__ BT,
    const float* __restrict__ bias, unsigned short* __restrict__ Cb,
    int M, int N, int K, int mode)
{
    __shared__ __align__(16) unsigned short As[64][40];
    __shared__ __align__(16) unsigned short Bs[128][40];

    const int tid  = threadIdx.x;
    const int wave = tid >> 6, lane = tid & 63;
    const int wm = wave >> 1, wn = wave & 1;
    const int quad = lane >> 4, l16 = lane & 15;
    const int m0 = blockIdx.y * 64, n0 = blockIdx.x * 128;
    const int nz = gridDim.z;
    const int klen = K / nz;
    const int kbase = blockIdx.z * klen;

    f32x4 acc[2][4] = {};

    for (int k0 = kbase; k0 < kbase + klen; k0 += 32) {
        {
            int r = tid >> 2, kc = (tid & 3) * 8;
            int gr = m0 + r;
            uint4 d = (gr < M) ? *(const uint4*)(A + (size_t)gr * K + k0 + kc)
                               : make_uint4(0u, 0u, 0u, 0u);
            *(uint4*)&As[r][kc] = d;
        }
        #pragma unroll
        for (int i = 0; i < 2; ++i) {
            int idx = tid + 256 * i;
            int r = idx >> 2, kc = (idx & 3) * 8;
            *(uint4*)&Bs[r][kc] = *(const uint4*)(BT + (size_t)(n0 + r) * K + k0 + kc);
        }
        __syncthreads();
        bf16x8 af[2], bfr[4];
        #pragma unroll
        for (int mi = 0; mi < 2; ++mi)
            af[mi] = *(const bf16x8*)&As[wm * 32 + mi * 16 + l16][quad * 8];
        #pragma unroll
        for (int ni = 0; ni < 4; ++ni)
            bfr[ni] = *(const bf16x8*)&Bs[wn * 64 + ni * 16 + l16][quad * 8];
        #pragma unroll
        for (int mi = 0; mi < 2; ++mi)
            #pragma unroll
            for (int ni = 0; ni < 4; ++ni)
                acc[mi][ni] = __builtin_amdgcn_mfma_f32_16x16x32_bf16(
                    af[mi], bfr[ni], acc[mi][ni], 0, 0, 0);
        __syncthreads();
    }

    const float* bz = (blockIdx.z == 0) ? bias : nullptr;
    unsigned short* Cz = Cb + (size_t)blockIdx.z * M * N;

    #pragma unroll
    for (int mi = 0; mi < 2; ++mi) {
        #pragma unroll
        for (int r = 0; r < 4; ++r) {
            int gm = m0 + wm * 32 + mi * 16 + quad * 4 + r;
            if (gm >= M) continue;
            #pragma unroll
            for (int ni = 0; ni < 4; ++ni) {
                int gn = n0 + wn * 64 + ni * 16 + l16;
                float v = acc[mi][ni][r] + (bz ? bz[gn] : 0.f);
                if (mode == 1) v = fmaxf(v, 0.f);
                Cz[(size_t)gm * N + gn] = f32_to_bf16(v);
            }
        }
    }
}

// ---------------------------------------------------------------------------
// Vectorized LN2: one wave per row; x fp32 + two bf16 split-K halves.
// ---------------------------------------------------------------------------
__global__ __launch_bounds__(256) void ln2v_kernel(
    const float* __restrict__ x, const unsigned short* __restrict__ f0,
    const unsigned short* __restrict__ f1,
    const float* __restrict__ g, const float* __restrict__ b,
    float* __restrict__ out)
{
    int row  = blockIdx.x * 4 + (threadIdx.x >> 6);
    int lane = threadIdx.x & 63;
    size_t base = (size_t)row * 256 + lane * 4;
    float4 xv = *(const float4*)(x + base);
    uint2 u0 = *(const uint2*)(f0 + base);
    uint2 u1 = *(const uint2*)(f1 + base);
    float t0 = xv.x + __uint_as_float(u0.x << 16)        + __uint_as_float(u1.x << 16);
    float t1 = xv.y + __uint_as_float(u0.x & 0xFFFF0000u) + __uint_as_float(u1.x & 0xFFFF0000u);
    float t2 = xv.z + __uint_as_float(u0.y << 16)        + __uint_as_float(u1.y << 16);
    float t3 = xv.w + __uint_as_float(u0.y & 0xFFFF0000u) + __uint_as_float(u1.y & 0xFFFF0000u);
    float s  = t0 + t1 + t2 + t3;
    float ss = t0 * t0 + t1 * t1 + t2 * t2 + t3 * t3;
    #pragma unroll
    for (int m = 1; m < 64; m <<= 1) {
        s  += __shfl_xor(s,  m, 64);
        ss += __shfl_xor(ss, m, 64);
    }
    float mu = s * (1.f / 256.f);
    float rs = rsqrtf(ss * (1.f / 256.f) - mu * mu + 1e-5f);
    float4 gv = *(const float4*)(g + lane * 4);
    float4 bv = *(const float4*)(b + lane * 4);
    float4 o;
    o.x = (t0 - mu) * rs * gv.x + bv.x;
    o.y = (t1 - mu) * rs * gv.y + bv.y;
    o.z = (t2 - mu) * rs * gv.z + bv.z;
    o.w = (t3 - mu) * rs * gv.w + bv.w;
    *(float4*)(out + base) = o;
}

// ---------------------------------------------------------------------------
extern "C" void kernel_launch(void* const* d_in, const int* in_sizes, int n_in,
                              void* d_out, int out_size, void* d_ws, size_t ws_size,
                              hipStream_t stream)
{
    const float* query   = (const float*)d_in[0];
    const float* value   = (const float*)d_in[2];
    const float* refpts  = (const float*)d_in[3];
    const int*   bevmask = (const int*)d_in[6];
    const float* W_value = (const float*)d_in[7];
    const float* b_value = (const float*)d_in[8];
    const float* W_off   = (const float*)d_in[9];
    const float* b_off   = (const float*)d_in[10];
    const float* W_attn  = (const float*)d_in[11];
    const float* b_attn  = (const float*)d_in[12];
    const float* W_out   = (const float*)d_in[13];
    const float* b_out   = (const float*)d_in[14];
    const float* ln1_g   = (const float*)d_in[15];
    const float* ln1_b   = (const float*)d_in[16];
    const float* W1      = (const float*)d_in[17];
    const float* b1      = (const float*)d_in[18];
    const float* W2      = (const float*)d_in[19];
    const float* b2      = (const float*)d_in[20];
    const float* ln2_g   = (const float*)d_in[21];
    const float* ln2_b   = (const float*)d_in[22];
    float* out = (float*)d_out;

    // workspace layout (byte offsets, temporal aliasing):
    //  [0)          vb fp8 12,255,744       (head -> sample)
    //  [0)          xbuf fp32 6,553,600     (projln1 -> ln2) [vb dead]
    //  [13,000,000) hbf bf16 13,107,200     (ffn1 -> ffn2)
    //  [27,000,000) qoffb bf16 3,276,800    (head -> sample)
    //  [27,000,000) xb16 bf16 3,276,800     (projln1 -> ffn1) [qoffb dead]
    //  [31,000,000) qawb bf16 1,638,400     (head -> sample)
    //  [33,000,000) outsum bf16 3,276,800   (sample -> projln1)
    //  [36,500,000) visb 25,600             (sample -> projln1)
    //  [36,600,000) wsT bf16 1,507,328      (wt_head/sample-tail -> GEMMs)
    //  [39,000,000) ffnout bf16 2x3,276,800 (ffn2 -> ln2)
    char* ws = (char*)d_ws;
    unsigned char*  vb     = (unsigned char*)(ws + 0);
    float*          xbuf   = (float*)(ws + 0);
    unsigned short* hbf    = (unsigned short*)(ws + 13000000);
    unsigned short* qoffb  = (unsigned short*)(ws + 27000000);
    unsigned short* xb16   = (unsigned short*)(ws + 27000000);
    unsigned short* qawb   = (unsigned short*)(ws + 31000000);
    unsigned short* outsum = (unsigned short*)(ws + 33000000);
    float*          visb   = (float*)(ws + 36500000);
    unsigned short* wsT    = (unsigned short*)(ws + 36600000);
    unsigned short* ffnout = (unsigned short*)(ws + 39000000);

    unsigned short* WvT = wsT;            // [256][256]
    unsigned short* WqT = wsT + 65536;    // [384][256]
    unsigned short* WoT = wsT + 163840;   // [256][256] (K-permuted)
    unsigned short* W1T = wsT + 229376;   // [1024][256]
    unsigned short* W2T = wsT + 491520;   // [256][1024]

    // L0: head-side weights -> transposed bf16 (160 blocks)
    wt_head_kernel<<<dim3(160), 256, 0, stream>>>(
        W_value, W_off, W_attn, wsT);
    // L1: value proj (750 blocks, fp8 out, ch-permuted) + query proj (300 blocks)
    head_kernel<<<dim3(1050), 256, 0, stream>>>(
        value, query, WvT, WqT, b_value, b_off, b_attn, vb, qoffb, qawb);
    // L2: sampling (3200) + tail weight transpose (576, overlapped)
    sample_kernel<<<dim3(3776), 256, 0, stream>>>(
        vb, qoffb, qawb, refpts, bevmask, W_out, W1, W2, outsum, visb, wsT);
    // L3: x = LN(outsum@WoT + residual) -> xbuf fp32 + xb16 bf16 (400 blocks)
    projln1_kernel<<<dim3(400), 256, 0, stream>>>(
        outsum, WoT, query, visb, b_out, ln1_g, ln1_b, xbuf, xb16);
    // L4: h = relu(xb16 @ W1 + b1), 800 blocks
    gemm64_kernel<<<dim3(8, 100, 1), 256, 0, stream>>>(
        xb16, W1T, b1, hbf, NQ, DFFN, 256, 1);
    // L5: ffnout[z] = bf16(h @ W2 (+b2 on z=0)), split-K x2
    gemm64_kernel<<<dim3(2, 100, 2), 256, 0, stream>>>(
        hbf, W2T, b2, ffnout, NQ, 256, DFFN, 2);
    // L6: out = LN(x + f0 + f1)
    ln2v_kernel<<<dim3(1600), 256, 0, stream>>>(
        xbuf, ffnout, ffnout + (size_t)NQ * 256, ln2_g, ln2_b, out);
}

// Round 10
// 279.471 us; speedup vs baseline: 1.0647x; 1.0062x over previous
//
#include <hip/hip_runtime.h>
#include <math.h>

#define NQ      6400
#define NCAMS   6
#define LTOT    7979
#define DM      256
#define DFFN    1024

typedef __attribute__((ext_vector_type(8))) short bf16x8;
typedef __attribute__((ext_vector_type(4))) float f32x4;
typedef __attribute__((ext_vector_type(2))) float f32x2;

__device__ inline unsigned short f32_to_bf16(float f) {
    unsigned u = __float_as_uint(f);
    unsigned r = u + 0x7FFF + ((u >> 16) & 1);   // round-to-nearest-even
    return (unsigned short)(r >> 16);
}

// pack 2 f32 -> 2 bf16 in one VALU op (RNE, same rounding as f32_to_bf16)
__device__ inline unsigned cvt_pk_bf16(float lo, float hi) {
    unsigned r;
    asm("v_cvt_pk_bf16_f32 %0, %1, %2" : "=v"(r) : "v"(lo), "v"(hi));
    return r;
}
// single f32 -> bf16 in one VALU op
__device__ inline unsigned short cvt1_bf16(float x) {
    return (unsigned short)cvt_pk_bf16(x, 0.f);
}

// ---------------------------------------------------------------------------
// wt_head: transpose+convert only the weights the head kernel needs.
// wsT layout (shorts): WvT@0, WqT@65536 ([384][256]). 160 blocks.
// ---------------------------------------------------------------------------
__global__ __launch_bounds__(256) void wt_head_kernel(
    const float* __restrict__ Wv, const float* __restrict__ Woff,
    const float* __restrict__ Wattn, unsigned short* __restrict__ wsT)
{
    int b = blockIdx.x;
    const float* src; int K, N, t0, dstoff;
    if (b < 64)       { src = Wv;    K = 256; N = 256; t0 = 0;   dstoff = 0; }
    else if (b < 128) { src = Woff;  K = 256; N = 256; t0 = 64;  dstoff = 65536; }
    else              { src = Wattn; K = 256; N = 128; t0 = 128; dstoff = 131072; }
    int t = b - t0;
    int ntn = N >> 5;
    int kt = t / ntn, nt = t - kt * ntn;
    __shared__ float tile[32][33];
    int tx = threadIdx.x & 31, ty = threadIdx.x >> 5;
    #pragma unroll
    for (int i = 0; i < 4; ++i)
        tile[ty + i * 8][tx] = src[(size_t)(kt * 32 + ty + i * 8) * N + nt * 32 + tx];
    __syncthreads();
    #pragma unroll
    for (int i = 0; i < 4; ++i) {
        int nn = nt * 32 + ty + i * 8;
        wsT[dstoff + (size_t)nn * K + kt * 32 + tx] = f32_to_bf16(tile[tx][ty + i * 8]);
    }
}

// ---------------------------------------------------------------------------
// head_kernel: merged value projection + query projections.
//  b <  750 : value proj (BM=BN=128) -> vb FP8 e4m3 head-major
//             (cam, head, pixel, 32ch PERMUTED c' = 2*(c&15)+(c>>4)), 32 B rows.
//             XCD pair-swizzle: blocks (2i,2i+1) share the 131 KB A-panel;
//             bijective chunked remap co-locates each pair on one XCD so the
//             second n-half's A-read hits that XCD's L2.
//  else     : query projections (BM=64): bx=0,1 -> qoff (bf16);
//             bx=2 -> softmax -> qaw (bf16)
// ---------------------------------------------------------------------------
__global__ __launch_bounds__(256) void head_kernel(
    const float* __restrict__ value, const float* __restrict__ query,
    const unsigned short* __restrict__ WvT, const unsigned short* __restrict__ WqT,
    const float* __restrict__ bv, const float* __restrict__ boff,
    const float* __restrict__ battn,
    unsigned char* __restrict__ vb, unsigned short* __restrict__ qoffb,
    unsigned short* __restrict__ qawb)
{
    __shared__ __align__(16) unsigned char smem[20480];
    const int b = blockIdx.x;
    const int tid = threadIdx.x;
    const int wave = tid >> 6, lane = tid & 63;
    const int wm = wave >> 1, wn = wave & 1;
    const int quad = lane >> 4, l16 = lane & 15;

    if (b < 750) {
        unsigned short (*As)[40] = (unsigned short(*)[40])smem;
        unsigned short (*Bs)[40] = (unsigned short(*)[40])(smem + 10240);
        // XCD pair-swizzle (XCD assignment assumed round-robin = blockIdx%8):
        // chunk c<6 holds 94 vids, c>=6 holds 93; vid pairs (2i,2i+1) stay
        // within a chunk except at 7 boundaries. Bijective over [0,750).
        const int c = b & 7, j = b >> 3;
        const int vid = (c < 6 ? c * 94 : 564 + (c - 6) * 93) + j;
        const int m0 = (vid >> 1) * 128, n0 = (vid & 1) * 128;
        const int M = NCAMS * LTOT;

        f32x4 acc[4][4] = {};

        for (int k0 = 0; k0 < 256; k0 += 32) {
            #pragma unroll
            for (int i = 0; i < 2; ++i) {          // A: 128x32 fp32 -> bf16
                int idx = tid + 256 * i;
                int r = idx >> 2, kc = (idx & 3) * 8;
                int gr = m0 + r;
                float4 f0, f1;
                if (gr < M) {
                    f0 = *(const float4*)(value + (size_t)gr * 256 + k0 + kc);
                    f1 = *(const float4*)(value + (size_t)gr * 256 + k0 + kc + 4);
                } else { f0 = make_float4(0.f,0.f,0.f,0.f); f1 = f0; }
                uint4 o;
                o.x = cvt_pk_bf16(f0.x, f0.y);
                o.y = cvt_pk_bf16(f0.z, f0.w);
                o.z = cvt_pk_bf16(f1.x, f1.y);
                o.w = cvt_pk_bf16(f1.z, f1.w);
                *(uint4*)&As[r][kc] = o;
            }
            #pragma unroll
            for (int i = 0; i < 2; ++i) {          // B: WvT bf16, uint4
                int idx = tid + 256 * i;
                int r = idx >> 2, kc = (idx & 3) * 8;
                *(uint4*)&Bs[r][kc] = *(const uint4*)(WvT + (size_t)(n0 + r) * 256 + k0 + kc);
            }
            __syncthreads();
            bf16x8 af[4], bfr[4];
            #pragma unroll
            for (int mi = 0; mi < 4; ++mi)
                af[mi] = *(const bf16x8*)&As[wm * 64 + mi * 16 + l16][quad * 8];
            #pragma unroll
            for (int ni = 0; ni < 4; ++ni)
                bfr[ni] = *(const bf16x8*)&Bs[wn * 64 + ni * 16 + l16][quad * 8];
            #pragma unroll
            for (int mi = 0; mi < 4; ++mi)
                #pragma unroll
                for (int ni = 0; ni < 4; ++ni)
                    acc[mi][ni] = __builtin_amdgcn_mfma_f32_16x16x32_bf16(
                        af[mi], bfr[ni], acc[mi][ni], 0, 0, 0);
            __syncthreads();
        }

        // epilogue: pack channel pairs (c, c+16) -> adjacent bytes (2c', 2c'+1)
        #pragma unroll
        for (int mi = 0; mi < 4; ++mi) {
            #pragma unroll
            for (int r = 0; r < 4; ++r) {
                int gm = m0 + wm * 64 + mi * 16 + quad * 4 + r;
                if (gm >= M) continue;
                int cam = gm / LTOT;
                int pix = gm - cam * LTOT;
                #pragma unroll
                for (int p = 0; p < 2; ++p) {
                    int gn0 = n0 + wn * 64 + p * 32 + l16;   // c = l16 (mod 32)
                    int head = gn0 >> 5;
                    float v0 = acc[mi][2 * p][r]     + bv[gn0];
                    float v1 = acc[mi][2 * p + 1][r] + bv[gn0 + 16];
                    int pk = __builtin_amdgcn_cvt_pk_fp8_f32(v0, v1, 0, false);
                    *(unsigned short*)(vb + (((size_t)(cam * 8 + head)) * LTOT + pix) * 32
                                       + 2 * l16) = (unsigned short)pk;
                }
            }
        }
    } else {
        unsigned short (*As)[40] = (unsigned short(*)[40])smem;
        unsigned short (*Bs)[40] = (unsigned short(*)[40])(smem + 5120);
        const int t = b - 750;
        const int bx = t / 100, by = t % 100;
        const int m0 = by * 64, n0 = bx * 128;
        const int is_attn = (bx == 2);

        f32x4 acc[2][4] = {};

        for (int k0 = 0; k0 < 256; k0 += 32) {
            {                                       // A: 64x32 fp32 -> bf16
                int r = tid >> 2, kc = (tid & 3) * 8;
                float4 f0 = *(const float4*)(query + (size_t)(m0 + r) * 256 + k0 + kc);
                float4 f1 = *(const float4*)(query + (size_t)(m0 + r) * 256 + k0 + kc + 4);
                uint4 o;
                o.x = cvt_pk_bf16(f0.x, f0.y);
                o.y = cvt_pk_bf16(f0.z, f0.w);
                o.z = cvt_pk_bf16(f1.x, f1.y);
                o.w = cvt_pk_bf16(f1.z, f1.w);
                *(uint4*)&As[r][kc] = o;
            }
            #pragma unroll
            for (int i = 0; i < 2; ++i) {           // B: WqT bf16, uint4
                int idx = tid + 256 * i;
                int r = idx >> 2, kc = (idx & 3) * 8;
                *(uint4*)&Bs[r][kc] = *(const uint4*)(WqT + (size_t)(n0 + r) * 256 + k0 + kc);
            }
            __syncthreads();
            bf16x8 af[2], bfr[4];
            #pragma unroll
            for (int mi = 0; mi < 2; ++mi)
                af[mi] = *(const bf16x8*)&As[wm * 32 + mi * 16 + l16][quad * 8];
            #pragma unroll
            for (int ni = 0; ni < 4; ++ni)
                bfr[ni] = *(const bf16x8*)&Bs[wn * 64 + ni * 16 + l16][quad * 8];
            #pragma unroll
            for (int mi = 0; mi < 2; ++mi)
                #pragma unroll
                for (int ni = 0; ni < 4; ++ni)
                    acc[mi][ni] = __builtin_amdgcn_mfma_f32_16x16x32_bf16(
                        af[mi], bfr[ni], acc[mi][ni], 0, 0, 0);
            __syncthreads();
        }

        if (is_attn) {
            #pragma unroll
            for (int mi = 0; mi < 2; ++mi) {
                #pragma unroll
                for (int r = 0; r < 4; ++r) {
                    int gm = m0 + wm * 32 + mi * 16 + quad * 4 + r;
                    #pragma unroll
                    for (int ni = 0; ni < 4; ++ni) {
                        int gn = wn * 64 + ni * 16 + l16;
                        float v = acc[mi][ni][r] + battn[gn];
                        float mx = v;
                        #pragma unroll
                        for (int s = 1; s < 16; s <<= 1)
                            mx = fmaxf(mx, __shfl_xor(mx, s, 64));
                        float e = __expf(v - mx);
                        float sum = e;
                        #pragma unroll
                        for (int s = 1; s < 16; s <<= 1)
                            sum += __shfl_xor(sum, s, 64);
                        qawb[(size_t)gm * 128 + gn] = f32_to_bf16(e / sum);
                    }
                }
            }
        } else {
            #pragma unroll
            for (int mi = 0; mi < 2; ++mi) {
                #pragma unroll
                for (int r = 0; r < 4; ++r) {
                    int gm = m0 + wm * 32 + mi * 16 + quad * 4 + r;
                    #pragma unroll
                    for (int ni = 0; ni < 4; ++ni) {
                        int gn = n0 + wn * 64 + ni * 16 + l16;
                        qoffb[(size_t)gm * 256 + gn] = f32_to_bf16(acc[mi][ni][r] + boff[gn]);
                    }
                }
            }
        }
    }
}

// ---------------------------------------------------------------------------
// sample_kernel: b < 3200 -> head-partitioned fp8 deformable sampling with
// packed f32x2 accumulation; b >= 3200 -> tail weight transpose.
// Gather phase batches all 8 corner loads of a camera (both tuples) into
// d[8] BEFORE consuming: 8 independent 16 B loads in flight per wave (was
// ~1-2, each fully latency-exposed). FP accumulation order unchanged ->
// bit-identical results. __launch_bounds__(256,6) matches the LDS-implied
// residency cap (26.6 KB -> 6 blocks/CU = 6 waves/SIMD) and gives the
// allocator the 85-VGPR budget (~80 needed) instead of the default 64-VGPR
// class that would spill the batch (R2/R4 lesson: never over-constrain).
// ---------------------------------------------------------------------------
__global__ __launch_bounds__(256, 6) void sample_kernel(
    const unsigned char* __restrict__ vb,  // (6, 8, 7979, 32) fp8 e4m3, ch-permuted
    const unsigned short* __restrict__ qoffb, // (6400, 256) bf16
    const unsigned short* __restrict__ qawb,  // (6400, 128) bf16
    const float* __restrict__ refpts,      // (6, 1, 6400, 4, 2)
    const int*   __restrict__ bev_mask,    // (6, 1, 6400, 4)
    const float* __restrict__ Wout, const float* __restrict__ W1,
    const float* __restrict__ W2,
    unsigned short* __restrict__ outsum,   // (6400, 256) bf16 (ch-permuted)
    float* __restrict__ visb,              // (6400)
    unsigned short* __restrict__ wsT)
{
    __shared__ __align__(16) unsigned s_tab[NCAMS][272][4];   // [cam][sq*17+tup][corner]
    __shared__ float s_vis[NCAMS][16];
    __shared__ int   s_nvis[16];

    const int bid = blockIdx.x;
    const int tid = threadIdx.x;

    if (bid >= 3200) {
        // ---- tail weight transpose (reuses s_tab as the LDS tile) ----
        int t = bid - 3200;
        const float* src; int K, N, dstoff;
        if (t < 64)       { src = Wout; K = 256;  N = 256;  dstoff = 163840; }
        else if (t < 320) { src = W1;   K = 256;  N = 1024; dstoff = 229376; t -= 64; }
        else              { src = W2;   K = 1024; N = 256;  dstoff = 491520; t -= 320; }
        int ntn = N >> 5;
        int kt = t / ntn, nt = t - kt * ntn;
        float (*tile)[33] = (float(*)[33])&s_tab[0][0][0];
        int tx = tid & 31, ty = tid >> 5;
        #pragma unroll
        for (int i = 0; i < 4; ++i)
            tile[ty + i * 8][tx] = src[(size_t)(kt * 32 + ty + i * 8) * N + nt * 32 + tx];
        __syncthreads();
        // WoT only: permute K index within each 32-channel head block to match
        // the vb/outsum channel interleave: c' = 2*(c&15) | (c>>4)
        int txp = (dstoff == 163840) ? (((tx & 15) << 1) | (tx >> 4)) : tx;
        #pragma unroll
        for (int i = 0; i < 4; ++i) {
            int nn = nt * 32 + ty + i * 8;
            wsT[dstoff + (size_t)nn * K + kt * 32 + txp] = f32_to_bf16(tile[tx][ty + i * 8]);
        }
        return;
    }

    const int h   = bid & 7;
    const int q0  = (bid >> 3) * 16;
    const int sq  = tid >> 4;
    const int tup = tid & 15;
    const int lvl = tup >> 2;
    const int n_s = q0 + sq;

    if (tid < 96) {
        int cam = tid >> 4, q = tid & 15;
        const int* bm = bev_mask + ((size_t)cam * NQ + q0 + q) * 4;
        s_vis[cam][q] = ((bm[0] + bm[1] + bm[2] + bm[3]) > 0) ? 1.f : 0.f;
    }
    __syncthreads();
    if (tid >= 32 && tid < 48) {
        int q = tid - 32;
        float s = 0.f;
        #pragma unroll
        for (int cam = 0; cam < NCAMS; ++cam) s += s_vis[cam][q];
        s_nvis[q] = (int)s;
    }

    unsigned uoff = *(const unsigned*)(qoffb + (size_t)n_s * 256 + h * 32 + tup * 2);
    const float offx  = __uint_as_float(uoff << 16);
    const float offy  = __uint_as_float(uoff & 0xFFFF0000u);
    const float my_aw = __uint_as_float((unsigned)qawb[(size_t)n_s * 128 + h * 16 + tup] << 16);
    const int Wl   = (lvl == 0) ? 100 : (lvl == 1) ? 50 : (lvl == 2) ? 25 : 13;
    const int Hl   = (lvl == 0) ? 60  : (lvl == 1) ? 30 : (lvl == 2) ? 15 : 8;
    const int base = (lvl == 0) ? 0   : (lvl == 1) ? 6000 : (lvl == 2) ? 7500 : 7875;
    const float dx = offx / (float)Wl;
    const float dy = offy / (float)Hl;
    const int tabi = sq * 17 + tup;

    float2 rp[NCAMS];
    #pragma unroll
    for (int k = 0; k < NCAMS; ++k)
        rp[k] = *(const float2*)(refpts + (((size_t)k * NQ + n_s) * 4 + lvl) * 2);
    __syncthreads();   // covers s_nvis writes

    #pragma unroll
    for (int k = 0; k < NCAMS; ++k) {
        float fx = (rp[k].x + dx) * (float)Wl - 0.5f;
        float fy = (rp[k].y + dy) * (float)Hl - 0.5f;
        float x0f = floorf(fx), y0f = floorf(fy);
        float lx = fx - x0f, ly = fy - y0f;
        int x0 = (int)x0f, y0 = (int)y0f;
        int x1 = x0 + 1, y1 = y0 + 1;
        float wb = my_aw * s_vis[k][sq];
        float w00 = (1.f - lx) * (1.f - ly) * wb;
        float w01 = lx * (1.f - ly) * wb;
        float w10 = (1.f - lx) * ly * wb;
        float w11 = lx * ly * wb;
        bool vx0 = (x0 >= 0) & (x0 < Wl), vx1 = (x1 >= 0) & (x1 < Wl);
        bool vy0 = (y0 >= 0) & (y0 < Hl), vy1 = (y1 >= 0) & (y1 < Hl);
        uint4 o;
        o.x = (vx0 & vy0) ? (((unsigned)(base + y0 * Wl + x0) << 16) | f32_to_bf16(w00)) : 0u;
        o.y = (vx1 & vy0) ? (((unsigned)(base + y0 * Wl + x1) << 16) | f32_to_bf16(w01)) : 0u;
        o.z = (vx0 & vy1) ? (((unsigned)(base + y1 * Wl + x0) << 16) | f32_to_bf16(w10)) : 0u;
        o.w = (vx1 & vy1) ? (((unsigned)(base + y1 * Wl + x1) << 16) | f32_to_bf16(w11)) : 0u;
        *(uint4*)&s_tab[k][tabi][0] = o;
    }
    __syncthreads();

    // ---- accumulate: tp = 8 tap-threads (2 tuples), cg2 = 2 ch-groups of 16 ----
    const int tp  = (tid >> 1) & 7;
    const int cg2 = tid & 1;

    f32x2 A[8] = {};

    #pragma unroll
    for (int k = 0; k < NCAMS; ++k) {
        const char* vkh = (const char*)vb + (size_t)(k * 8 + h) * (LTOT * 32) + cg2 * 16;
        uint4 t4a = *(const uint4*)&s_tab[k][sq * 17 + tp * 2 + 0][0];
        uint4 t4b = *(const uint4*)&s_tab[k][sq * 17 + tp * 2 + 1][0];
        unsigned tc[8] = { t4a.x, t4a.y, t4a.z, t4a.w,
                           t4b.x, t4b.y, t4b.z, t4b.w };
        uint4 d[8];
        #pragma unroll
        for (int i = 0; i < 8; ++i)             // 8 loads issued back-to-back
            d[i] = *(const uint4*)(vkh + ((size_t)(tc[i] >> 16) << 5));
        #pragma unroll
        for (int i = 0; i < 8; ++i) {           // consume in same order (bit-identical)
            float w = __uint_as_float(tc[i] << 16);
            f32x2 w2 = {w, w};
            A[0] += w2 * __builtin_amdgcn_cvt_pk_f32_fp8(d[i].x, false);
            A[1] += w2 * __builtin_amdgcn_cvt_pk_f32_fp8(d[i].x, true);
            A[2] += w2 * __builtin_amdgcn_cvt_pk_f32_fp8(d[i].y, false);
            A[3] += w2 * __builtin_amdgcn_cvt_pk_f32_fp8(d[i].y, true);
            A[4] += w2 * __builtin_amdgcn_cvt_pk_f32_fp8(d[i].z, false);
            A[5] += w2 * __builtin_amdgcn_cvt_pk_f32_fp8(d[i].z, true);
            A[6] += w2 * __builtin_amdgcn_cvt_pk_f32_fp8(d[i].w, false);
            A[7] += w2 * __builtin_amdgcn_cvt_pk_f32_fp8(d[i].w, true);
        }
    }

    // reduce across the 8 tap-threads (lane bits 1..3)
    #pragma unroll
    for (int i = 0; i < 8; ++i) {
        float x0 = A[i].x, x1 = A[i].y;
        x0 += __shfl_xor(x0, 2, 64); x1 += __shfl_xor(x1, 2, 64);
        x0 += __shfl_xor(x0, 4, 64); x1 += __shfl_xor(x1, 4, 64);
        x0 += __shfl_xor(x0, 8, 64); x1 += __shfl_xor(x1, 8, 64);
        A[i].x = x0; A[i].y = x1;
    }

    if ((tid & 14) == 0) {          // tp == 0: two writers per query (cg2 = 0,1)
        int nv = s_nvis[sq];
        float sc = 1.f / (float)(nv > 0 ? nv : 1);
        uint4 o0, o1;
        o0.x = f32_to_bf16(A[0].x * sc) | ((unsigned)f32_to_bf16(A[0].y * sc) << 16);
        o0.y = f32_to_bf16(A[1].x * sc) | ((unsigned)f32_to_bf16(A[1].y * sc) << 16);
        o0.z = f32_to_bf16(A[2].x * sc) | ((unsigned)f32_to_bf16(A[2].y * sc) << 16);
        o0.w = f32_to_bf16(A[3].x * sc) | ((unsigned)f32_to_bf16(A[3].y * sc) << 16);
        o1.x = f32_to_bf16(A[4].x * sc) | ((unsigned)f32_to_bf16(A[4].y * sc) << 16);
        o1.y = f32_to_bf16(A[5].x * sc) | ((unsigned)f32_to_bf16(A[5].y * sc) << 16);
        o1.z = f32_to_bf16(A[6].x * sc) | ((unsigned)f32_to_bf16(A[6].y * sc) << 16);
        o1.w = f32_to_bf16(A[7].x * sc) | ((unsigned)f32_to_bf16(A[7].y * sc) << 16);
        *(uint4*)(outsum + (size_t)n_s * 256 + h * 32 + cg2 * 16)     = o0;
        *(uint4*)(outsum + (size_t)n_s * 256 + h * 32 + cg2 * 16 + 8) = o1;
    }
    if (h == 0 && tid < 16) visb[q0 + tid] = (s_nvis[tid] > 0) ? 1.f : 0.f;
}

// ---------------------------------------------------------------------------
// projln1 v2: BM=16, 400 blocks. Each wave owns a 64-col slice; LN1
// reduction crosses 4 waves via LDS.
// x = LN(outsum@WoT + residual algebra) -> xout fp32 + xb16 bf16.
// ---------------------------------------------------------------------------
__global__ __launch_bounds__(256) void projln1_kernel(
    const unsigned short* __restrict__ A, const unsigned short* __restrict__ BT,
    const float* __restrict__ query, const float* __restrict__ visb,
    const float* __restrict__ b_out, const float* __restrict__ g,
    const float* __restrict__ b,
    float* __restrict__ xout, unsigned short* __restrict__ xb16)
{
    __shared__ __align__(16) unsigned short As[16][40];
    __shared__ __align__(16) unsigned short Bs[256][40];
    __shared__ float sred[4][4][4];    // [quad][r][wave]
    __shared__ float ssred[4][4][4];
    __shared__ float s_mu[16], s_rs[16];

    const int tid  = threadIdx.x;
    const int wave = tid >> 6, lane = tid & 63;
    const int quad = lane >> 4, l16 = lane & 15;
    const int m0 = blockIdx.x * 16;

    f32x4 acc[4] = {};

    for (int k0 = 0; k0 < 256; k0 += 32) {
        {
            int r = tid >> 4, kc = (tid & 15) * 2;
            *(unsigned*)&As[r][kc] = *(const unsigned*)(A + (size_t)(m0 + r) * 256 + k0 + kc);
        }
        {
            const unsigned short* src = BT + (size_t)tid * 256 + k0;
            *(uint4*)&Bs[tid][0]  = *(const uint4*)(src);
            *(uint4*)&Bs[tid][8]  = *(const uint4*)(src + 8);
            *(uint4*)&Bs[tid][16] = *(const uint4*)(src + 16);
            *(uint4*)&Bs[tid][24] = *(const uint4*)(src + 24);
        }
        __syncthreads();
        bf16x8 af = *(const bf16x8*)&As[l16][quad * 8];
        #pragma unroll
        for (int ni = 0; ni < 4; ++ni) {
            bf16x8 bfr = *(const bf16x8*)&Bs[wave * 64 + ni * 16 + l16][quad * 8];
            acc[ni] = __builtin_amdgcn_mfma_f32_16x16x32_bf16(af, bfr, acc[ni], 0, 0, 0);
        }
        __syncthreads();
    }

    float vals[4][4];
    #pragma unroll
    for (int r = 0; r < 4; ++r) {
        int gm = m0 + quad * 4 + r;
        float vs = visb[gm];
        float s = 0.f, ss = 0.f;
        #pragma unroll
        for (int ni = 0; ni < 4; ++ni) {
            int gn = wave * 64 + ni * 16 + l16;
            float v = acc[ni][r] + vs * b_out[gn]
                    + query[(size_t)gm * 256 + gn] * (1.f + vs);
            vals[ni][r] = v;
            s += v; ss += v * v;
        }
        #pragma unroll
        for (int m = 1; m < 16; m <<= 1) {
            s  += __shfl_xor(s,  m, 64);
            ss += __shfl_xor(ss, m, 64);
        }
        if (l16 == 0) {
            sred[quad][r][wave]  = s;
            ssred[quad][r][wave] = ss;
        }
    }
    __syncthreads();
    if (tid < 16) {
        int lq = tid >> 2, lr = tid & 3;
        float s  = sred[lq][lr][0]  + sred[lq][lr][1]  + sred[lq][lr][2]  + sred[lq][lr][3];
        float ss = ssred[lq][lr][0] + ssred[lq][lr][1] + ssred[lq][lr][2] + ssred[lq][lr][3];
        float mu = s * (1.f / 256.f);
        float var = ss * (1.f / 256.f) - mu * mu;
        s_mu[tid] = mu;                 // tid == lq*4+lr == local row
        s_rs[tid] = rsqrtf(var + 1e-5f);
    }
    __syncthreads();

    #pragma unroll
    for (int r = 0; r < 4; ++r) {
        int rowl = quad * 4 + r;
        int gm = m0 + rowl;
        float mu = s_mu[rowl], rs = s_rs[rowl];
        #pragma unroll
        for (int ni = 0; ni < 4; ++ni) {
            int gn = wave * 64 + ni * 16 + l16;
            float res = (vals[ni][r] - mu) * rs * g[gn] + b[gn];
            xout[(size_t)gm * 256 + gn] = res;
            xb16[(size_t)gm * 256 + gn] = cvt1_bf16(res);
        }
    }
}

// ---------------------------------------------------------------------------
// MFMA bf16 GEMM, BM=64 BN=128 BK=32, bf16 A + BT. Split-K over gridDim.z.
// mode 1: relu -> bf16 out; mode 2: plain bf16 out (split-K partials).
// ---------------------------------------------------------------------------
__global__ __launch_bounds__(256) void gemm64_kernel(
    const unsigned short* __restrict__ A, const unsigned short* __restrict__ BT,
    const float* __restrict__ bias, unsigned short* __restrict__ Cb,
    int M, int N, int K, int mode)
{
    __shared__ __align__(16) unsigned short As[64][40];
    __shared__ __align__(16) unsigned short Bs[128][40];

    const int tid  = threadIdx.x;
    const int wave = tid >> 6, lane = tid & 63;
    const int wm = wave >> 1, wn = wave & 1;
    const int quad = lane >> 4, l16 = lane & 15;
    const int m0 = blockIdx.y * 64, n0 = blockIdx.x * 128;
    const int nz = gridDim.z;
    const int klen = K / nz;
    const int kbase = blockIdx.z * klen;

    f32x4 acc[2][4] = {};

    for (int k0 = kbase; k0 < kbase + klen; k0 += 32) {
        {
            int r = tid >> 2, kc = (tid & 3) * 8;
            int gr = m0 + r;
            uint4 d = (gr < M) ? *(const uint4*)(A + (size_t)gr * K + k0 + kc)
                               : make_uint4(0u, 0u, 0u, 0u);
            *(uint4*)&As[r][kc] = d;
        }
        #pragma unroll
        for (int i = 0; i < 2; ++i) {
            int idx = tid + 256 * i;
            int r = idx >> 2, kc = (idx & 3) * 8;
            *(uint4*)&Bs[r][kc] = *(const uint4*)(BT + (size_t)(n0 + r) * K + k0 + kc);
        }
        __syncthreads();
        bf16x8 af[2], bfr[4];
        #pragma unroll
        for (int mi = 0; mi < 2; ++mi)
            af[mi] = *(const bf16x8*)&As[wm * 32 + mi * 16 + l16][quad * 8];
        #pragma unroll
        for (int ni = 0; ni < 4; ++ni)
            bfr[ni] = *(const bf16x8*)&Bs[wn * 64 + ni * 16 + l16][quad * 8];
        #pragma unroll
        for (int mi = 0; mi < 2; ++mi)
            #pragma unroll
            for (int ni = 0; ni < 4; ++ni)
                acc[mi][ni] = __builtin_amdgcn_mfma_f32_16x16x32_bf16(
                    af[mi], bfr[ni], acc[mi][ni], 0, 0, 0);
        __syncthreads();
    }

    const float* bz = (blockIdx.z == 0) ? bias : nullptr;
    unsigned short* Cz = Cb + (size_t)blockIdx.z * M * N;

    #pragma unroll
    for (int mi = 0; mi < 2; ++mi) {
        #pragma unroll
        for (int r = 0; r < 4; ++r) {
            int gm = m0 + wm * 32 + mi * 16 + quad * 4 + r;
            if (gm >= M) continue;
            #pragma unroll
            for (int ni = 0; ni < 4; ++ni) {
                int gn = n0 + wn * 64 + ni * 16 + l16;
                float v = acc[mi][ni][r] + (bz ? bz[gn] : 0.f);
                if (mode == 1) v = fmaxf(v, 0.f);
                Cz[(size_t)gm * N + gn] = f32_to_bf16(v);
            }
        }
    }
}

// ---------------------------------------------------------------------------
// Vectorized LN2: one wave per row; x fp32 + two bf16 split-K halves.
// ---------------------------------------------------------------------------
__global__ __launch_bounds__(256) void ln2v_kernel(
    const float* __restrict__ x, const unsigned short* __restrict__ f0,
    const unsigned short* __restrict__ f1,
    const float* __restrict__ g, const float* __restrict__ b,
    float* __restrict__ out)
{
    int row  = blockIdx.x * 4 + (threadIdx.x >> 6);
    int lane = threadIdx.x & 63;
    size_t base = (size_t)row * 256 + lane * 4;
    float4 xv = *(const float4*)(x + base);
    uint2 u0 = *(const uint2*)(f0 + base);
    uint2 u1 = *(const uint2*)(f1 + base);
    float t0 = xv.x + __uint_as_float(u0.x << 16)        + __uint_as_float(u1.x << 16);
    float t1 = xv.y + __uint_as_float(u0.x & 0xFFFF0000u) + __uint_as_float(u1.x & 0xFFFF0000u);
    float t2 = xv.z + __uint_as_float(u0.y << 16)        + __uint_as_float(u1.y << 16);
    float t3 = xv.w + __uint_as_float(u0.y & 0xFFFF0000u) + __uint_as_float(u1.y & 0xFFFF0000u);
    float s  = t0 + t1 + t2 + t3;
    float ss = t0 * t0 + t1 * t1 + t2 * t2 + t3 * t3;
    #pragma unroll
    for (int m = 1; m < 64; m <<= 1) {
        s  += __shfl_xor(s,  m, 64);
        ss += __shfl_xor(ss, m, 64);
    }
    float mu = s * (1.f / 256.f);
    float rs = rsqrtf(ss * (1.f / 256.f) - mu * mu + 1e-5f);
    float4 gv = *(const float4*)(g + lane * 4);
    float4 bv = *(const float4*)(b + lane * 4);
    float4 o;
    o.x = (t0 - mu) * rs * gv.x + bv.x;
    o.y = (t1 - mu) * rs * gv.y + bv.y;
    o.z = (t2 - mu) * rs * gv.z + bv.z;
    o.w = (t3 - mu) * rs * gv.w + bv.w;
    *(float4*)(out + base) = o;
}

// ---------------------------------------------------------------------------
extern "C" void kernel_launch(void* const* d_in, const int* in_sizes, int n_in,
                              void* d_out, int out_size, void* d_ws, size_t ws_size,
                              hipStream_t stream)
{
    const float* query   = (const float*)d_in[0];
    const float* value   = (const float*)d_in[2];
    const float* refpts  = (const float*)d_in[3];
    const int*   bevmask = (const int*)d_in[6];
    const float* W_value = (const float*)d_in[7];
    const float* b_value = (const float*)d_in[8];
    const float* W_off   = (const float*)d_in[9];
    const float* b_off   = (const float*)d_in[10];
    const float* W_attn  = (const float*)d_in[11];
    const float* b_attn  = (const float*)d_in[12];
    const float* W_out   = (const float*)d_in[13];
    const float* b_out   = (const float*)d_in[14];
    const float* ln1_g   = (const float*)d_in[15];
    const float* ln1_b   = (const float*)d_in[16];
    const float* W1      = (const float*)d_in[17];
    const float* b1      = (const float*)d_in[18];
    const float* W2      = (const float*)d_in[19];
    const float* b2      = (const float*)d_in[20];
    const float* ln2_g   = (const float*)d_in[21];
    const float* ln2_b   = (const float*)d_in[22];
    float* out = (float*)d_out;

    // workspace layout (byte offsets, temporal aliasing):
    //  [0)          vb fp8 12,255,744       (head -> sample)
    //  [0)          xbuf fp32 6,553,600     (projln1 -> ln2) [vb dead]
    //  [13,000,000) hbf bf16 13,107,200     (ffn1 -> ffn2)
    //  [27,000,000) qoffb bf16 3,276,800    (head -> sample)
    //  [27,000,000) xb16 bf16 3,276,800     (projln1 -> ffn1) [qoffb dead]
    //  [31,000,000) qawb bf16 1,638,400     (head -> sample)
    //  [33,000,000) outsum bf16 3,276,800   (sample -> projln1)
    //  [36,500,000) visb 25,600             (sample -> projln1)
    //  [36,600,000) wsT bf16 1,507,328      (wt_head/sample-tail -> GEMMs)
    //  [39,000,000) ffnout bf16 2x3,276,800 (ffn2 -> ln2)
    char* ws = (char*)d_ws;
    unsigned char*  vb     = (unsigned char*)(ws + 0);
    float*          xbuf   = (float*)(ws + 0);
    unsigned short* hbf    = (unsigned short*)(ws + 13000000);
    unsigned short* qoffb  = (unsigned short*)(ws + 27000000);
    unsigned short* xb16   = (unsigned short*)(ws + 27000000);
    unsigned short* qawb   = (unsigned short*)(ws + 31000000);
    unsigned short* outsum = (unsigned short*)(ws + 33000000);
    float*          visb   = (float*)(ws + 36500000);
    unsigned short* wsT    = (unsigned short*)(ws + 36600000);
    unsigned short* ffnout = (unsigned short*)(ws + 39000000);

    unsigned short* WvT = wsT;            // [256][256]
    unsigned short* WqT = wsT + 65536;    // [384][256]
    unsigned short* WoT = wsT + 163840;   // [256][256] (K-permuted)
    unsigned short* W1T = wsT + 229376;   // [1024][256]
    unsigned short* W2T = wsT + 491520;   // [256][1024]

    // L0: head-side weights -> transposed bf16 (160 blocks)
    wt_head_kernel<<<dim3(160), 256, 0, stream>>>(
        W_value, W_off, W_attn, wsT);
    // L1: value proj (750 blocks, fp8 out, ch-permuted, XCD pair-swizzle)
    //     + query proj (300 blocks)
    head_kernel<<<dim3(1050), 256, 0, stream>>>(
        value, query, WvT, WqT, b_value, b_off, b_attn, vb, qoffb, qawb);
    // L2: sampling (3200, batched gathers) + tail weight transpose (576)
    sample_kernel<<<dim3(3776), 256, 0, stream>>>(
        vb, qoffb, qawb, refpts, bevmask, W_out, W1, W2, outsum, visb, wsT);
    // L3: x = LN(outsum@WoT + residual) -> xbuf fp32 + xb16 bf16 (400 blocks)
    projln1_kernel<<<dim3(400), 256, 0, stream>>>(
        outsum, WoT, query, visb, b_out, ln1_g, ln1_b, xbuf, xb16);
    // L4: h = relu(xb16 @ W1 + b1), 800 blocks
    gemm64_kernel<<<dim3(8, 100, 1), 256, 0, stream>>>(
        xb16, W1T, b1, hbf, NQ, DFFN, 256, 1);
    // L5: ffnout[z] = bf16(h @ W2 (+b2 on z=0)), split-K x2
    gemm64_kernel<<<dim3(2, 100, 2), 256, 0, stream>>>(
        hbf, W2T, b2, ffnout, NQ, 256, DFFN, 2);
    // L6: out = LN(x + f0 + f1)
    ln2v_kernel<<<dim3(1600), 256, 0, stream>>>(
        xbuf, ffnout, ffnout + (size_t)NQ * 256, ln2_g, ln2_b, out);
}